// Round 5
// baseline (717.941 us; speedup 1.0000x reference)
//
#include <hip/hip_runtime.h>

#define NPTS 12288
#define LQPAD 1800
#define LPAD2 1856
#define EPSBN 1e-4f

typedef _Float16 half8 __attribute__((ext_vector_type(8)));
typedef _Float16 half4 __attribute__((ext_vector_type(4)));
typedef float floatx4 __attribute__((ext_vector_type(4)));

// ---------------- small GEMM: C[n,64] = A[n,64] @ W[64,64] (+ optional fp16 copy) --------
__global__ __launch_bounds__(256) void gemm64(const float* A, const float* __restrict__ W,
                                              float* C, _Float16* C16, int n) {
    __shared__ __align__(16) float Wt[64 * 68];
    __shared__ __align__(16) float As[16][64];
    int t = threadIdx.x;
    int f = t & 63, rg = t >> 6;
    int row0 = blockIdx.x * 16;
    for (int i = t; i < 4096; i += 256) {
        int c = i >> 6, ff = i & 63;
        Wt[ff * 68 + c] = W[i];
    }
    for (int rr = rg; rr < 16; rr += 4) As[rr][f] = A[(row0 + rr) * 64 + f];
    __syncthreads();
    float acc[4] = {0.f, 0.f, 0.f, 0.f};
    const float* wrow = Wt + f * 68;
#pragma unroll
    for (int cq = 0; cq < 64; cq += 4) {
        float4 wq = *(const float4*)(wrow + cq);
#pragma unroll
        for (int rr = 0; rr < 4; rr++) {
            float4 aq = *(const float4*)(&As[rg * 4 + rr][cq]);
            acc[rr] += aq.x * wq.x + aq.y * wq.y + aq.z * wq.z + aq.w * wq.w;
        }
    }
#pragma unroll
    for (int rr = 0; rr < 4; rr++) {
        C[(row0 + rg * 4 + rr) * 64 + f] = acc[rr];
        if (C16) C16[(row0 + rg * 4 + rr) * 64 + f] = (_Float16)acc[rr];
    }
}

// ---------------- W pack: [ntap][64f][64o] fp32 -> B-fragment-major fp16 ----------------
__global__ __launch_bounds__(256) void pack_w(const float* __restrict__ W, _Float16* __restrict__ Wf) {
    int tap = blockIdx.x;
    int t = threadIdx.x;
    int lane = t & 63, fg = t >> 6;
    int quad = lane >> 4, qi = lane & 15;
    const float* Wk = W + tap * 4096;
#pragma unroll
    for (int u = 0; u < 2; u++) {
        int frag = fg * 2 + u;
        int s = frag >> 2, ct = frag & 3;
        half8 v;
#pragma unroll
        for (int j = 0; j < 8; j++) v[j] = (_Float16)Wk[(s * 32 + quad * 8 + j) * 64 + ct * 16 + qi];
        *(half8*)(Wf + (size_t)tap * 4096 + frag * 512 + lane * 8) = v;
    }
}

// ---------------- gather conv, MFMA, zero-LDS zero-barrier ----------------
__global__ __launch_bounds__(256) void gconv_mfma(const _Float16* __restrict__ Xh,
                                                  const int* __restrict__ idx,
                                                  const _Float16* __restrict__ Wf,
                                                  float* __restrict__ OUT, int nk) {
    int t = threadIdx.x;
    int lane = t & 63, wv = t >> 6;
    int quad = lane >> 4, qi = lane & 15;
    int row0 = blockIdx.x * 64 + wv * 16;
    floatx4 Oacc[4];
#pragma unroll
    for (int ct = 0; ct < 4; ct++) Oacc[ct] = floatx4{0.f, 0.f, 0.f, 0.f};
    const int* ip = idx + (size_t)(row0 + qi) * nk;
    for (int k = 0; k < nk; k++) {
        int j = ip[k];
        half8 a0 = half8{0, 0, 0, 0, 0, 0, 0, 0};
        half8 a1 = half8{0, 0, 0, 0, 0, 0, 0, 0};
        if (j >= 0) {
            a0 = *(const half8*)(Xh + (size_t)j * 64 + quad * 8);
            a1 = *(const half8*)(Xh + (size_t)j * 64 + 32 + quad * 8);
        }
        const _Float16* wk = Wf + (size_t)k * 4096;
#pragma unroll
        for (int ct = 0; ct < 4; ct++) {
            half8 b0 = *(const half8*)(wk + ct * 512 + lane * 8);
            half8 b1 = *(const half8*)(wk + (4 + ct) * 512 + lane * 8);
            Oacc[ct] = __builtin_amdgcn_mfma_f32_16x16x32_f16(a0, b0, Oacc[ct], 0, 0, 0);
            Oacc[ct] = __builtin_amdgcn_mfma_f32_16x16x32_f16(a1, b1, Oacc[ct], 0, 0, 0);
        }
    }
    int orow = row0 + quad * 4;
#pragma unroll
    for (int ct = 0; ct < 4; ct++)
#pragma unroll
        for (int r = 0; r < 4; r++) OUT[(size_t)(orow + r) * 64 + ct * 16 + qi] = Oacc[ct][r];
}

// ---------------- BN statistics ----------------
__global__ __launch_bounds__(256) void bn_stats(const float* __restrict__ X, const float* __restrict__ X2,
                                                float* __restrict__ stats, int n) {
    int t = threadIdx.x;
    int f = t & 63, g = t >> 6;
    float s = 0.f, ss = 0.f;
    for (int r = blockIdx.x * 4 + g; r < n; r += gridDim.x * 4) {
        float v = X[r * 64 + f];
        if (X2) v += X2[r * 64 + f];
        s += v;
        ss += v * v;
    }
    __shared__ float sh[2][4][64];
    sh[0][g][f] = s;
    sh[1][g][f] = ss;
    __syncthreads();
    if (g == 0) {
        s = sh[0][0][f] + sh[0][1][f] + sh[0][2][f] + sh[0][3][f];
        ss = sh[1][0][f] + sh[1][1][f] + sh[1][2][f] + sh[1][3][f];
        atomicAdd(&stats[f], s);
        atomicAdd(&stats[64 + f], ss);
    }
}

__global__ __launch_bounds__(256) void bn_apply(const float* __restrict__ X, const float* __restrict__ X2,
                                                const float* R, float* OUT, _Float16* OUT16,
                                                const float* __restrict__ stats,
                                                const float* __restrict__ gamma,
                                                const float* __restrict__ beta, int n, int do_relu) {
    int i = blockIdx.x * 256 + threadIdx.x;
    if (i >= n * 64) return;
    int f = i & 63;
    float inv_n = 1.f / (float)n;
    float mean = stats[f] * inv_n;
    float var = stats[64 + f] * inv_n - mean * mean;
    float rstd = rsqrtf(var + EPSBN);
    float v = X[i];
    if (X2) v += X2[i];
    v = (v - mean) * rstd * gamma[f] + beta[f];
    if (R) v += R[i];
    if (do_relu) v = fmaxf(v, 0.f);
    if (OUT) OUT[i] = v;
    if (OUT16) OUT16[i] = (_Float16)v;
}

// ---------------- prep: fp32 -> fp16 (A split hi/lo; B direct) ----------------
__global__ __launch_bounds__(256) void prep_split(const float* __restrict__ a, const float* __restrict__ b,
                                                  _Float16* __restrict__ Ah, _Float16* __restrict__ Al,
                                                  _Float16* __restrict__ Bh) {
    int i = blockIdx.x * 256 + threadIdx.x;
    if (i >= NPTS * 64) return;
    float av = a[i];
    _Float16 h = (_Float16)av;
    Ah[i] = h;
    Al[i] = (_Float16)(av - (float)h);
    Bh[i] = (_Float16)b[i];
}

// ---------------- V transpose (stage-1) ----------------
__global__ __launch_bounds__(256) void vtrans(const float* __restrict__ V, _Float16* __restrict__ Vt) {
    __shared__ float T[64][65];
    int t = threadIdx.x;
    int k0 = blockIdx.x * 64;
    for (int idx = t; idx < 4096; idx += 256) {
        int r = idx >> 6, c = idx & 63;
        T[r][c] = V[(k0 + r) * 64 + c];
    }
    __syncthreads();
    int f = t >> 2, ks = (t & 3) * 16;
    half8 a, b;
#pragma unroll
    for (int j = 0; j < 8; j++) {
        a[j] = (_Float16)T[ks + j][f];
        b[j] = (_Float16)T[ks + 8 + j][f];
    }
    *(half8*)(Vt + f * NPTS + k0 + ks) = a;
    *(half8*)(Vt + f * NPTS + k0 + ks + 8) = b;
}

// ---------------- V transpose (stage-2) ----------------
__global__ __launch_bounds__(256) void vtrans2(const float* __restrict__ V, const int* __restrict__ pad_idx,
                                               _Float16* __restrict__ Vt2) {
    __shared__ float T[64][65];
    int t = threadIdx.x;
    int b = blockIdx.y;
    int k0 = blockIdx.x * 64;
    const int* prow = pad_idx + b * LQPAD;
    for (int idx = t; idx < 4096; idx += 256) {
        int r = idx >> 6, c = idx & 63;
        int p = k0 + r;
        int flat = (p < LQPAD) ? prow[p] : -1;
        T[r][c] = (flat >= 0) ? V[(size_t)flat * 64 + c] : 0.f;
    }
    __syncthreads();
    int f = t >> 2, ks = (t & 3) * 16;
    half8 a, bb;
#pragma unroll
    for (int j = 0; j < 8; j++) {
        a[j] = (_Float16)T[ks + j][f];
        bb[j] = (_Float16)T[ks + 8 + j][f];
    }
    _Float16* dst = Vt2 + ((size_t)b * 64 + f) * LPAD2 + k0 + ks;
    *(half8*)(dst) = a;
    *(half8*)(dst + 8) = bb;
}

// ---------------- per-batch valid counts ----------------
__global__ __launch_bounds__(256) void count_valid(const int* __restrict__ pad_idx, int* __restrict__ counts) {
    int b = blockIdx.x;
    int t = threadIdx.x;
    int s = 0;
    for (int i = t; i < LQPAD; i += 256) s += (pad_idx[b * LQPAD + i] >= 0) ? 1 : 0;
    for (int off = 32; off > 0; off >>= 1) s += __shfl_xor(s, off);
    if ((t & 63) == 0) atomicAdd(&counts[b], s);
}

// ---------------- Stage-1 flash attention, MFMA, direct-load, zero-barrier ----------------
// All K/V fragments loaded per-lane straight from global (L1/L2-shared across waves);
// only the per-wave P^T transpose touches LDS (no __syncthreads anywhere).
__global__ __launch_bounds__(256) void flash1_mfma(const _Float16* __restrict__ Qh,
                                                   const _Float16* __restrict__ Ql,
                                                   const _Float16* __restrict__ Kh,
                                                   const _Float16* __restrict__ Vt,
                                                   float* __restrict__ Op, float* __restrict__ Ms,
                                                   float* __restrict__ Ls) {
    __shared__ __align__(16) _Float16 PTF[4][2 * 512];
    int t = threadIdx.x;
    int lane = t & 63, wv = t >> 6;
    int quad = lane >> 4, qi = lane & 15;
    int qb = blockIdx.x, sp = blockIdx.y;
    int q0w = qb * 64 + wv * 16;
    int qrow = q0w + qi;

    half8 qh[2], ql[2];
#pragma unroll
    for (int s = 0; s < 2; s++) {
        qh[s] = *(const half8*)(Qh + qrow * 64 + s * 32 + quad * 8);
        ql[s] = *(const half8*)(Ql + qrow * 64 + s * 32 + quad * 8);
    }
    floatx4 Oacc[4];
#pragma unroll
    for (int ft = 0; ft < 4; ft++) Oacc[ft] = floatx4{0.f, 0.f, 0.f, 0.f};
    float m_i = -1e30f, l_i = 0.f;

    for (int it = 0; it < 48; it++) {
        int k0 = sp * 3072 + it * 64;
        // direct fragment loads (compiler free to issue all early; no barriers)
        half8 ka[4][2], va[4][2];
#pragma unroll
        for (int kt = 0; kt < 4; kt++)
#pragma unroll
            for (int s = 0; s < 2; s++)
                ka[kt][s] = *(const half8*)(Kh + (size_t)(k0 + kt * 16 + qi) * 64 + s * 32 + quad * 8);
#pragma unroll
        for (int ft = 0; ft < 4; ft++)
#pragma unroll
            for (int s = 0; s < 2; s++)
                va[ft][s] = *(const half8*)(Vt + (size_t)(ft * 16 + qi) * NPTS + k0 + s * 32 + quad * 8);
        floatx4 st[4];
#pragma unroll
        for (int kt = 0; kt < 4; kt++) {
            floatx4 acc = floatx4{0.f, 0.f, 0.f, 0.f};
#pragma unroll
            for (int s = 0; s < 2; s++) {
                acc = __builtin_amdgcn_mfma_f32_16x16x32_f16(ka[kt][s], qh[s], acc, 0, 0, 0);
                acc = __builtin_amdgcn_mfma_f32_16x16x32_f16(ka[kt][s], ql[s], acc, 0, 0, 0);
            }
            st[kt] = acc;
        }
        float mloc = -1e30f;
#pragma unroll
        for (int kt = 0; kt < 4; kt++)
#pragma unroll
            for (int r = 0; r < 4; r++) mloc = fmaxf(mloc, st[kt][r]);
        mloc = fmaxf(mloc, __shfl_xor(mloc, 16));
        mloc = fmaxf(mloc, __shfl_xor(mloc, 32));
        float m_new = fmaxf(m_i, mloc);
        float alpha = __expf(m_i - m_new);
        float ps = 0.f;
#pragma unroll
        for (int kt = 0; kt < 4; kt++) {
            half4 pk;
#pragma unroll
            for (int r = 0; r < 4; r++) {
                float p = __expf(st[kt][r] - m_new);
                ps += p;
                pk[r] = (_Float16)p;
            }
            int s = kt >> 1;
            int qd2 = (kt & 1) * 2 + (quad >> 1);
            *(half4*)(&PTF[wv][(s * 64 + qd2 * 16 + qi) * 8 + (quad & 1) * 4]) = pk;
        }
        ps += __shfl_xor(ps, 16);
        ps += __shfl_xor(ps, 32);
        l_i = l_i * alpha + ps;
        m_i = m_new;
#pragma unroll
        for (int ft = 0; ft < 4; ft++) Oacc[ft] *= alpha;
        half8 pb[2];
#pragma unroll
        for (int s = 0; s < 2; s++) pb[s] = *(const half8*)(&PTF[wv][(s * 64 + lane) * 8]);
#pragma unroll
        for (int ft = 0; ft < 4; ft++)
#pragma unroll
            for (int s = 0; s < 2; s++)
                Oacc[ft] = __builtin_amdgcn_mfma_f32_16x16x32_f16(va[ft][s], pb[s], Oacc[ft], 0, 0, 0);
    }
#pragma unroll
    for (int ft = 0; ft < 4; ft++) {
        floatx4 o = Oacc[ft];
        *(floatx4*)(Op + ((size_t)sp * NPTS + q0w + qi) * 64 + ft * 16 + quad * 4) = o;
    }
    if (lane < 16) {
        Ms[sp * NPTS + q0w + lane] = m_i;
        Ls[sp * NPTS + q0w + lane] = l_i;
    }
}

// ---------------- combine key-split partials ----------------
__global__ __launch_bounds__(256) void merge1(const float* __restrict__ Op, const float* __restrict__ Ms,
                                              const float* __restrict__ Ls, float* __restrict__ xr) {
    int i = blockIdx.x * 256 + threadIdx.x;
    int q = i >> 4, f4 = (i & 15) * 4;
    float m[4], M = -1e30f;
#pragma unroll
    for (int s = 0; s < 4; s++) {
        m[s] = Ms[s * NPTS + q];
        M = fmaxf(M, m[s]);
    }
    float L = 0.f;
    float4 acc = {0.f, 0.f, 0.f, 0.f};
#pragma unroll
    for (int s = 0; s < 4; s++) {
        float w = __expf(m[s] - M);
        L += Ls[s * NPTS + q] * w;
        float4 o = *(const float4*)(Op + ((size_t)s * NPTS + q) * 64 + f4);
        acc.x += o.x * w;
        acc.y += o.y * w;
        acc.z += o.z * w;
        acc.w += o.w * w;
    }
    float inv = 1.f / L;
    float4 r = {acc.x * inv, acc.y * inv, acc.z * inv, acc.w * inv};
    *(float4*)(xr + q * 64 + f4) = r;
}

// ---------------- Stage-2 ragged flash attention, MFMA, direct-load, zero-barrier --------
__global__ __launch_bounds__(256) void flash2_mfma(const _Float16* __restrict__ Qh,
                                                   const _Float16* __restrict__ Ql,
                                                   const _Float16* __restrict__ Kh,
                                                   const _Float16* __restrict__ Vt2,
                                                   const int* __restrict__ pad_idx,
                                                   const int* __restrict__ counts,
                                                   _Float16* __restrict__ O) {
    int b = blockIdx.y;
    int c = counts[b];
    int qb = blockIdx.x;
    if (qb * 64 >= c) return;
    __shared__ __align__(16) _Float16 PTF[4][2 * 512];
    int t = threadIdx.x;
    int lane = t & 63, wv = t >> 6;
    int quad = lane >> 4, qi = lane & 15;
    const int* prow = pad_idx + b * LQPAD;
    int p_q = qb * 64 + wv * 16 + qi;
    int flat_q = (p_q < LQPAD) ? prow[p_q] : -1;

    half8 qh[2], ql[2];
#pragma unroll
    for (int s = 0; s < 2; s++) {
        if (flat_q >= 0) {
            qh[s] = *(const half8*)(Qh + (size_t)flat_q * 64 + s * 32 + quad * 8);
            ql[s] = *(const half8*)(Ql + (size_t)flat_q * 64 + s * 32 + quad * 8);
        } else {
            qh[s] = half8{0, 0, 0, 0, 0, 0, 0, 0};
            ql[s] = half8{0, 0, 0, 0, 0, 0, 0, 0};
        }
    }
    floatx4 Oacc[4];
#pragma unroll
    for (int ft = 0; ft < 4; ft++) Oacc[ft] = floatx4{0.f, 0.f, 0.f, 0.f};
    float m_i = -1e30f, l_i = 0.f;
    const _Float16* VtB = Vt2 + (size_t)b * 64 * LPAD2;

    int nt = (c + 63) >> 6;
    for (int it = 0; it < nt; it++) {
        int k0 = it * 64;
        half8 ka[4][2], va[4][2];
#pragma unroll
        for (int kt = 0; kt < 4; kt++) {
            int kp = k0 + kt * 16 + qi;
            int flat = (kp < c) ? prow[kp] : -1;
#pragma unroll
            for (int s = 0; s < 2; s++)
                ka[kt][s] = (flat >= 0) ? *(const half8*)(Kh + (size_t)flat * 64 + s * 32 + quad * 8)
                                        : half8{0, 0, 0, 0, 0, 0, 0, 0};
        }
#pragma unroll
        for (int ft = 0; ft < 4; ft++)
#pragma unroll
            for (int s = 0; s < 2; s++)
                va[ft][s] = *(const half8*)(VtB + (size_t)(ft * 16 + qi) * LPAD2 + k0 + s * 32 + quad * 8);
        floatx4 st[4];
#pragma unroll
        for (int kt = 0; kt < 4; kt++) {
            floatx4 acc = floatx4{0.f, 0.f, 0.f, 0.f};
#pragma unroll
            for (int s = 0; s < 2; s++) {
                acc = __builtin_amdgcn_mfma_f32_16x16x32_f16(ka[kt][s], qh[s], acc, 0, 0, 0);
                acc = __builtin_amdgcn_mfma_f32_16x16x32_f16(ka[kt][s], ql[s], acc, 0, 0, 0);
            }
            st[kt] = acc;
        }
        float mloc = -1e30f;
#pragma unroll
        for (int kt = 0; kt < 4; kt++)
#pragma unroll
            for (int r = 0; r < 4; r++) mloc = fmaxf(mloc, st[kt][r]);
        mloc = fmaxf(mloc, __shfl_xor(mloc, 16));
        mloc = fmaxf(mloc, __shfl_xor(mloc, 32));
        float m_new = fmaxf(m_i, mloc);
        float alpha = __expf(m_i - m_new);
        float ps = 0.f;
#pragma unroll
        for (int kt = 0; kt < 4; kt++) {
            half4 pk;
#pragma unroll
            for (int r = 0; r < 4; r++) {
                int kpos = k0 + kt * 16 + quad * 4 + r;
                float p = (kpos < c) ? __expf(st[kt][r] - m_new) : 0.f;
                ps += p;
                pk[r] = (_Float16)p;
            }
            int s = kt >> 1;
            int qd2 = (kt & 1) * 2 + (quad >> 1);
            *(half4*)(&PTF[wv][(s * 64 + qd2 * 16 + qi) * 8 + (quad & 1) * 4]) = pk;
        }
        ps += __shfl_xor(ps, 16);
        ps += __shfl_xor(ps, 32);
        l_i = l_i * alpha + ps;
        m_i = m_new;
#pragma unroll
        for (int ft = 0; ft < 4; ft++) Oacc[ft] *= alpha;
        half8 pb[2];
#pragma unroll
        for (int s = 0; s < 2; s++) pb[s] = *(const half8*)(&PTF[wv][(s * 64 + lane) * 8]);
#pragma unroll
        for (int ft = 0; ft < 4; ft++)
#pragma unroll
            for (int s = 0; s < 2; s++)
                Oacc[ft] = __builtin_amdgcn_mfma_f32_16x16x32_f16(va[ft][s], pb[s], Oacc[ft], 0, 0, 0);
    }
    if (flat_q >= 0) {
        float inv = 1.f / l_i;
#pragma unroll
        for (int ft = 0; ft < 4; ft++) {
            half4 o;
#pragma unroll
            for (int r = 0; r < 4; r++) o[r] = (_Float16)(Oacc[ft][r] * inv);
            *(half4*)(O + (size_t)flat_q * 64 + ft * 16 + quad * 4) = o;
        }
    }
}

extern "C" void kernel_launch(void* const* d_in, const int* in_sizes, int n_in,
                              void* d_out, int out_size, void* d_ws, size_t ws_size,
                              hipStream_t stream) {
    const float* x_dec = (const float*)d_in[0];
    const float* x_enc = (const float*)d_in[1];
    const float* Wp1 = (const float*)d_in[2];
    const float* Wq = (const float*)d_in[3];
    const float* Wk = (const float*)d_in[4];
    const float* Wv = (const float*)d_in[5];
    const float* Wt_ = (const float*)d_in[6];
    const float* Wq1 = (const float*)d_in[7];
    const float* Wk1 = (const float*)d_in[8];
    const float* Wv1 = (const float*)d_in[9];
    const float* Wdown = (const float*)d_in[10];
    const float* W3t = (const float*)d_in[11];
    const float* W3a = (const float*)d_in[12];
    const float* W3b = (const float*)d_in[13];
    const float* bn_g = (const float*)d_in[14];
    const float* bn_b = (const float*)d_in[15];
    const int* nbr = (const int*)d_in[16];
    const int* kv_nbr = (const int*)d_in[17];
    const int* pad_idx = (const int*)d_in[18];
    float* out = (float*)d_out;
    float* ws = (float*)d_ws;

    const int N = NPTS;
    const size_t BUF = (size_t)N * 64;
    float* xd = ws;
    float* q = ws + BUF;
    float* ke = ws + 2 * BUF;
    float* ve = ws + 3 * BUF;
    float* xr = ws + 4 * BUF;
    float* kv = ws + 5 * BUF;
    float* o2 = ws + 6 * BUF;
    float* xr2 = ws + 7 * BUF;
    float* z2 = ws + 8 * BUF;
    float* stats = ws + 9 * BUF;
    float* Op = q;
    int* counts = (int*)(stats + 768);
    float* Ms = stats + 1024;
    float* Ls = Ms + 4 * NPTS;

    _Float16* Qh = (_Float16*)kv;
    _Float16* Ql = Qh + BUF;
    _Float16* Kh = (_Float16*)o2;
    _Float16* Vt = Kh + BUF;
    _Float16* Qh1 = (_Float16*)kv;
    _Float16* Ql1 = Qh1 + BUF;
    _Float16* Kh1 = (_Float16*)o2;
    _Float16* Vt2 = (_Float16*)xr;
    _Float16* q1h = (_Float16*)xr;
    _Float16* z2h = (_Float16*)z2;
    _Float16* Wf_dt = z2h + BUF;
    _Float16* Wf_d = Wf_dt;
    _Float16* Wf_3t = Wf_dt + (size_t)8 * 4096;
    _Float16* xrh = (_Float16*)xr;
    _Float16* xr2h = (_Float16*)xr2;
    _Float16* Wf_ab = (_Float16*)kv;
    _Float16* Wf_3a = Wf_ab;
    _Float16* Wf_3b = Wf_ab + (size_t)27 * 4096;

    hipMemsetAsync(stats, 0, 1024 * sizeof(float), stream);

    dim3 B(256);
    int gR = N / 16;
    int gC = N / 64;
    int gS = 64;
    int gE = (N * 64) / 256;

    pack_w<<<8, B, 0, stream>>>(Wdown, Wf_d);
    pack_w<<<27, B, 0, stream>>>(W3t, Wf_3t);

    gemm64<<<gR, B, 0, stream>>>(x_dec, Wp1, xd, nullptr, N);
    gemm64<<<gR, B, 0, stream>>>(xd, Wq, q, nullptr, N);
    gemm64<<<gR, B, 0, stream>>>(x_enc, Wk, ke, nullptr, N);
    gemm64<<<gR, B, 0, stream>>>(x_enc, Wv, ve, nullptr, N);
    prep_split<<<gE, B, 0, stream>>>(q, ke, Qh, Ql, Kh);
    vtrans<<<N / 64, B, 0, stream>>>(ve, Vt);
    flash1_mfma<<<dim3(N / 64, 4), B, 0, stream>>>(Qh, Ql, Kh, Vt, Op, Ms, Ls);
    merge1<<<(N * 16) / 256, B, 0, stream>>>(Op, Ms, Ls, xr);
    gemm64<<<gR, B, 0, stream>>>(xr, Wt_, xr, nullptr, N);
    bn_stats<<<gS, B, 0, stream>>>(xr, nullptr, stats + 0, N);
    bn_apply<<<gE, B, 0, stream>>>(xr, nullptr, xd, xd, nullptr, stats + 0, bn_g + 0, bn_b + 0, N, 0);

    gemm64<<<gR, B, 0, stream>>>(xd, Wq1, q, q1h, N);
    gconv_mfma<<<gC, B, 0, stream>>>(q1h, kv_nbr, Wf_d, kv, 8);
    bn_stats<<<gS, B, 0, stream>>>(kv, nullptr, stats + 128, N);
    bn_apply<<<gE, B, 0, stream>>>(kv, nullptr, nullptr, kv, nullptr, stats + 128, bn_g + 64, bn_b + 64, N, 0);
    gemm64<<<gR, B, 0, stream>>>(kv, Wk1, ke, nullptr, N);
    gemm64<<<gR, B, 0, stream>>>(kv, Wv1, ve, nullptr, N);
    prep_split<<<gE, B, 0, stream>>>(q, ke, Qh1, Ql1, Kh1);
    vtrans2<<<dim3(LPAD2 / 64, 8), B, 0, stream>>>(ve, pad_idx, Vt2);
    count_valid<<<8, B, 0, stream>>>(pad_idx, counts);
    flash2_mfma<<<dim3(LPAD2 / 64, 8), B, 0, stream>>>(Qh1, Ql1, Kh1, Vt2, pad_idx, counts, z2h);
    pack_w<<<27, B, 0, stream>>>(W3a, Wf_3a);
    pack_w<<<27, B, 0, stream>>>(W3b, Wf_3b);
    gconv_mfma<<<gC, B, 0, stream>>>(z2h, nbr, Wf_3t, xr2, 27);
    bn_stats<<<gS, B, 0, stream>>>(xr2, nullptr, stats + 256, N);
    bn_apply<<<gE, B, 0, stream>>>(xr2, nullptr, xd, xd, nullptr, stats + 256, bn_g + 128, bn_b + 128, N, 0);

    bn_stats<<<gS, B, 0, stream>>>(xd, nullptr, stats + 384, N);
    bn_apply<<<gE, B, 0, stream>>>(xd, nullptr, nullptr, nullptr, xrh, stats + 384, bn_g + 192, bn_b + 192, N, 1);
    gconv_mfma<<<gC, B, 0, stream>>>(xrh, nbr, Wf_3a, o2, 27);
    bn_stats<<<gS, B, 0, stream>>>(o2, nullptr, stats + 512, N);
    bn_apply<<<gE, B, 0, stream>>>(o2, nullptr, nullptr, nullptr, xr2h, stats + 512, bn_g + 256, bn_b + 256, N, 1);
    gconv_mfma<<<gC, B, 0, stream>>>(xr2h, nbr, Wf_3b, z2, 27);
    bn_stats<<<gS, B, 0, stream>>>(xd, z2, stats + 640, N);
    bn_apply<<<gE, B, 0, stream>>>(xd, z2, nullptr, out, nullptr, stats + 640, bn_g + 320, bn_b + 320, N, 1);
}

// Round 6
// 547.445 us; speedup vs baseline: 1.3114x; 1.3114x over previous
//
#include <hip/hip_runtime.h>

#define NPTS 12288
#define LQPAD 1800
#define LPAD2 1856
#define EPSBN 1e-4f

typedef _Float16 half8 __attribute__((ext_vector_type(8)));
typedef _Float16 half4 __attribute__((ext_vector_type(4)));
typedef float floatx4 __attribute__((ext_vector_type(4)));

// ---------------- small GEMM: C[n,64] = A[n,64] @ W[64,64] (+ optional fp16 copy) --------
__global__ __launch_bounds__(256) void gemm64(const float* A, const float* __restrict__ W,
                                              float* C, _Float16* C16, int n) {
    __shared__ __align__(16) float Wt[64 * 68];
    __shared__ __align__(16) float As[16][64];
    int t = threadIdx.x;
    int f = t & 63, rg = t >> 6;
    int row0 = blockIdx.x * 16;
    for (int i = t; i < 4096; i += 256) {
        int c = i >> 6, ff = i & 63;
        Wt[ff * 68 + c] = W[i];
    }
    for (int rr = rg; rr < 16; rr += 4) As[rr][f] = A[(row0 + rr) * 64 + f];
    __syncthreads();
    float acc[4] = {0.f, 0.f, 0.f, 0.f};
    const float* wrow = Wt + f * 68;
#pragma unroll
    for (int cq = 0; cq < 64; cq += 4) {
        float4 wq = *(const float4*)(wrow + cq);
#pragma unroll
        for (int rr = 0; rr < 4; rr++) {
            float4 aq = *(const float4*)(&As[rg * 4 + rr][cq]);
            acc[rr] += aq.x * wq.x + aq.y * wq.y + aq.z * wq.z + aq.w * wq.w;
        }
    }
#pragma unroll
    for (int rr = 0; rr < 4; rr++) {
        C[(row0 + rg * 4 + rr) * 64 + f] = acc[rr];
        if (C16) C16[(row0 + rg * 4 + rr) * 64 + f] = (_Float16)acc[rr];
    }
}

// ---------------- W pack ----------------
__global__ __launch_bounds__(256) void pack_w(const float* __restrict__ W, _Float16* __restrict__ Wf) {
    int tap = blockIdx.x;
    int t = threadIdx.x;
    int lane = t & 63, fg = t >> 6;
    int quad = lane >> 4, qi = lane & 15;
    const float* Wk = W + tap * 4096;
#pragma unroll
    for (int u = 0; u < 2; u++) {
        int frag = fg * 2 + u;
        int s = frag >> 2, ct = frag & 3;
        half8 v;
#pragma unroll
        for (int j = 0; j < 8; j++) v[j] = (_Float16)Wk[(s * 32 + quad * 8 + j) * 64 + ct * 16 + qi];
        *(half8*)(Wf + (size_t)tap * 4096 + frag * 512 + lane * 8) = v;
    }
}

// ---------------- gather conv, MFMA, zero-LDS zero-barrier ----------------
__global__ __launch_bounds__(256) void gconv_mfma(const _Float16* __restrict__ Xh,
                                                  const int* __restrict__ idx,
                                                  const _Float16* __restrict__ Wf,
                                                  float* __restrict__ OUT, int nk) {
    int t = threadIdx.x;
    int lane = t & 63, wv = t >> 6;
    int quad = lane >> 4, qi = lane & 15;
    int row0 = blockIdx.x * 64 + wv * 16;
    floatx4 Oacc[4];
#pragma unroll
    for (int ct = 0; ct < 4; ct++) Oacc[ct] = floatx4{0.f, 0.f, 0.f, 0.f};
    const int* ip = idx + (size_t)(row0 + qi) * nk;
    for (int k = 0; k < nk; k++) {
        int j = ip[k];
        half8 a0 = half8{0, 0, 0, 0, 0, 0, 0, 0};
        half8 a1 = half8{0, 0, 0, 0, 0, 0, 0, 0};
        if (j >= 0) {
            a0 = *(const half8*)(Xh + (size_t)j * 64 + quad * 8);
            a1 = *(const half8*)(Xh + (size_t)j * 64 + 32 + quad * 8);
        }
        const _Float16* wk = Wf + (size_t)k * 4096;
#pragma unroll
        for (int ct = 0; ct < 4; ct++) {
            half8 b0 = *(const half8*)(wk + ct * 512 + lane * 8);
            half8 b1 = *(const half8*)(wk + (4 + ct) * 512 + lane * 8);
            Oacc[ct] = __builtin_amdgcn_mfma_f32_16x16x32_f16(a0, b0, Oacc[ct], 0, 0, 0);
            Oacc[ct] = __builtin_amdgcn_mfma_f32_16x16x32_f16(a1, b1, Oacc[ct], 0, 0, 0);
        }
    }
    int orow = row0 + quad * 4;
#pragma unroll
    for (int ct = 0; ct < 4; ct++)
#pragma unroll
        for (int r = 0; r < 4; r++) OUT[(size_t)(orow + r) * 64 + ct * 16 + qi] = Oacc[ct][r];
}

// ---------------- BN statistics ----------------
__global__ __launch_bounds__(256) void bn_stats(const float* __restrict__ X, const float* __restrict__ X2,
                                                float* __restrict__ stats, int n) {
    int t = threadIdx.x;
    int f = t & 63, g = t >> 6;
    float s = 0.f, ss = 0.f;
    for (int r = blockIdx.x * 4 + g; r < n; r += gridDim.x * 4) {
        float v = X[r * 64 + f];
        if (X2) v += X2[r * 64 + f];
        s += v;
        ss += v * v;
    }
    __shared__ float sh[2][4][64];
    sh[0][g][f] = s;
    sh[1][g][f] = ss;
    __syncthreads();
    if (g == 0) {
        s = sh[0][0][f] + sh[0][1][f] + sh[0][2][f] + sh[0][3][f];
        ss = sh[1][0][f] + sh[1][1][f] + sh[1][2][f] + sh[1][3][f];
        atomicAdd(&stats[f], s);
        atomicAdd(&stats[64 + f], ss);
    }
}

__global__ __launch_bounds__(256) void bn_apply(const float* __restrict__ X, const float* __restrict__ X2,
                                                const float* R, float* OUT, _Float16* OUT16,
                                                const float* __restrict__ stats,
                                                const float* __restrict__ gamma,
                                                const float* __restrict__ beta, int n, int do_relu) {
    int i = blockIdx.x * 256 + threadIdx.x;
    if (i >= n * 64) return;
    int f = i & 63;
    float inv_n = 1.f / (float)n;
    float mean = stats[f] * inv_n;
    float var = stats[64 + f] * inv_n - mean * mean;
    float rstd = rsqrtf(var + EPSBN);
    float v = X[i];
    if (X2) v += X2[i];
    v = (v - mean) * rstd * gamma[f] + beta[f];
    if (R) v += R[i];
    if (do_relu) v = fmaxf(v, 0.f);
    if (OUT) OUT[i] = v;
    if (OUT16) OUT16[i] = (_Float16)v;
}

// ---------------- prep: fp32 -> fp16 (A split hi/lo; B direct) ----------------
__global__ __launch_bounds__(256) void prep_split(const float* __restrict__ a, const float* __restrict__ b,
                                                  _Float16* __restrict__ Ah, _Float16* __restrict__ Al,
                                                  _Float16* __restrict__ Bh) {
    int i = blockIdx.x * 256 + threadIdx.x;
    if (i >= NPTS * 64) return;
    float av = a[i];
    _Float16 h = (_Float16)av;
    Ah[i] = h;
    Al[i] = (_Float16)(av - (float)h);
    Bh[i] = (_Float16)b[i];
}

// ---------------- V transpose (stage-1) ----------------
__global__ __launch_bounds__(256) void vtrans(const float* __restrict__ V, _Float16* __restrict__ Vt) {
    __shared__ float T[64][65];
    int t = threadIdx.x;
    int k0 = blockIdx.x * 64;
    for (int idx = t; idx < 4096; idx += 256) {
        int r = idx >> 6, c = idx & 63;
        T[r][c] = V[(k0 + r) * 64 + c];
    }
    __syncthreads();
    int f = t >> 2, ks = (t & 3) * 16;
    half8 a, b;
#pragma unroll
    for (int j = 0; j < 8; j++) {
        a[j] = (_Float16)T[ks + j][f];
        b[j] = (_Float16)T[ks + 8 + j][f];
    }
    *(half8*)(Vt + f * NPTS + k0 + ks) = a;
    *(half8*)(Vt + f * NPTS + k0 + ks + 8) = b;
}

// ---------------- V transpose (stage-2) ----------------
__global__ __launch_bounds__(256) void vtrans2(const float* __restrict__ V, const int* __restrict__ pad_idx,
                                               _Float16* __restrict__ Vt2) {
    __shared__ float T[64][65];
    int t = threadIdx.x;
    int b = blockIdx.y;
    int k0 = blockIdx.x * 64;
    const int* prow = pad_idx + b * LQPAD;
    for (int idx = t; idx < 4096; idx += 256) {
        int r = idx >> 6, c = idx & 63;
        int p = k0 + r;
        int flat = (p < LQPAD) ? prow[p] : -1;
        T[r][c] = (flat >= 0) ? V[(size_t)flat * 64 + c] : 0.f;
    }
    __syncthreads();
    int f = t >> 2, ks = (t & 3) * 16;
    half8 a, bb;
#pragma unroll
    for (int j = 0; j < 8; j++) {
        a[j] = (_Float16)T[ks + j][f];
        bb[j] = (_Float16)T[ks + 8 + j][f];
    }
    _Float16* dst = Vt2 + ((size_t)b * 64 + f) * LPAD2 + k0 + ks;
    *(half8*)(dst) = a;
    *(half8*)(dst + 8) = bb;
}

// ---------------- per-batch valid counts ----------------
__global__ __launch_bounds__(256) void count_valid(const int* __restrict__ pad_idx, int* __restrict__ counts) {
    int b = blockIdx.x;
    int t = threadIdx.x;
    int s = 0;
    for (int i = t; i < LQPAD; i += 256) s += (pad_idx[b * LQPAD + i] >= 0) ? 1 : 0;
    for (int off = 32; off > 0; off >>= 1) s += __shfl_xor(s, off);
    if ((t & 63) == 0) atomicAdd(&counts[b], s);
}

// ---------------- Stage-1 flash attention, MFMA, LDS-staged, 2 q-subtiles/wave -----------
// grid (96, 8): x = 128-query block (4 waves x 32 q-rows), y = key split (1536 keys, 24 tiles).
// K/V LDS fragments are read once per wave per tile and reused for both q-subtiles
// (LDS reads/MFMA 0.42 vs 0.75 in the 16-row version). Partials written fp16.
__global__ __launch_bounds__(256, 3) void flash1_mfma(const _Float16* __restrict__ Qh,
                                                      const _Float16* __restrict__ Ql,
                                                      const _Float16* __restrict__ Kh,
                                                      const _Float16* __restrict__ Vt,
                                                      _Float16* __restrict__ Op,
                                                      float* __restrict__ Ms,
                                                      float* __restrict__ Ls) {
    __shared__ __align__(16) _Float16 KsF[8 * 512];
    __shared__ __align__(16) _Float16 VsF[8 * 512];
    __shared__ __align__(16) _Float16 PTF[4][2 * 1024];  // per wave, per q-subtile
    int t = threadIdx.x;
    int lane = t & 63, wv = t >> 6;
    int quad = lane >> 4, qi = lane & 15;
    int qb = blockIdx.x, sp = blockIdx.y;
    int q0w = qb * 128 + wv * 32;

    half8 qh[2][2], ql[2][2];
#pragma unroll
    for (int sub = 0; sub < 2; sub++)
#pragma unroll
        for (int s = 0; s < 2; s++) {
            int qrow = q0w + sub * 16 + qi;
            qh[sub][s] = *(const half8*)(Qh + (size_t)qrow * 64 + s * 32 + quad * 8);
            ql[sub][s] = *(const half8*)(Ql + (size_t)qrow * 64 + s * 32 + quad * 8);
        }
    floatx4 Oacc[2][4];
#pragma unroll
    for (int sub = 0; sub < 2; sub++)
#pragma unroll
        for (int ft = 0; ft < 4; ft++) Oacc[sub][ft] = floatx4{0.f, 0.f, 0.f, 0.f};
    float m_i[2] = {-1e30f, -1e30f}, l_i[2] = {0.f, 0.f};

    for (int it = 0; it < 24; it++) {
        int k0 = sp * 1536 + it * 64;
        __syncthreads();
#pragma unroll
        for (int u = 0; u < 4; u++) {
            int frag = wv + 4 * u;
            if (frag < 8) {
                int kt = frag >> 1, s = frag & 1;
                int key = k0 + kt * 16 + qi;
                *(half8*)(KsF + frag * 512 + lane * 8) =
                    *(const half8*)(Kh + (size_t)key * 64 + s * 32 + quad * 8);
            } else {
                int fr = frag - 8;
                int ft = fr >> 1, s = fr & 1;
                int f = ft * 16 + qi;
                *(half8*)(VsF + fr * 512 + lane * 8) =
                    *(const half8*)(Vt + (size_t)f * NPTS + k0 + s * 32 + quad * 8);
            }
        }
        __syncthreads();
        // K fragments once, reused for both q-subtiles
        half8 ka[4][2];
#pragma unroll
        for (int kt = 0; kt < 4; kt++)
#pragma unroll
            for (int s = 0; s < 2; s++) ka[kt][s] = *(const half8*)(KsF + (kt * 2 + s) * 512 + lane * 8);
        floatx4 st[2][4];
#pragma unroll
        for (int sub = 0; sub < 2; sub++)
#pragma unroll
            for (int kt = 0; kt < 4; kt++) {
                floatx4 acc = floatx4{0.f, 0.f, 0.f, 0.f};
#pragma unroll
                for (int s = 0; s < 2; s++) {
                    acc = __builtin_amdgcn_mfma_f32_16x16x32_f16(ka[kt][s], qh[sub][s], acc, 0, 0, 0);
                    acc = __builtin_amdgcn_mfma_f32_16x16x32_f16(ka[kt][s], ql[sub][s], acc, 0, 0, 0);
                }
                st[sub][kt] = acc;
            }
        // online softmax per subtile
#pragma unroll
        for (int sub = 0; sub < 2; sub++) {
            float mloc = -1e30f;
#pragma unroll
            for (int kt = 0; kt < 4; kt++)
#pragma unroll
                for (int r = 0; r < 4; r++) mloc = fmaxf(mloc, st[sub][kt][r]);
            mloc = fmaxf(mloc, __shfl_xor(mloc, 16));
            mloc = fmaxf(mloc, __shfl_xor(mloc, 32));
            float m_new = fmaxf(m_i[sub], mloc);
            float alpha = __expf(m_i[sub] - m_new);
            float ps = 0.f;
#pragma unroll
            for (int kt = 0; kt < 4; kt++) {
                half4 pk;
#pragma unroll
                for (int r = 0; r < 4; r++) {
                    float p = __expf(st[sub][kt][r] - m_new);
                    ps += p;
                    pk[r] = (_Float16)p;
                }
                int s = kt >> 1;
                int qd2 = (kt & 1) * 2 + (quad >> 1);
                *(half4*)(&PTF[wv][sub * 1024 + (s * 64 + qd2 * 16 + qi) * 8 + (quad & 1) * 4]) = pk;
            }
            ps += __shfl_xor(ps, 16);
            ps += __shfl_xor(ps, 32);
            l_i[sub] = l_i[sub] * alpha + ps;
            m_i[sub] = m_new;
#pragma unroll
            for (int ft = 0; ft < 4; ft++) Oacc[sub][ft] *= alpha;
        }
        // PV with V fragments read once, reused for both q-subtiles
        half8 pb[2][2];
#pragma unroll
        for (int sub = 0; sub < 2; sub++)
#pragma unroll
            for (int s = 0; s < 2; s++)
                pb[sub][s] = *(const half8*)(&PTF[wv][sub * 1024 + (s * 64 + lane) * 8]);
#pragma unroll
        for (int ft = 0; ft < 4; ft++)
#pragma unroll
            for (int s = 0; s < 2; s++) {
                half8 v = *(const half8*)(VsF + (ft * 2 + s) * 512 + lane * 8);
                Oacc[0][ft] = __builtin_amdgcn_mfma_f32_16x16x32_f16(v, pb[0][s], Oacc[0][ft], 0, 0, 0);
                Oacc[1][ft] = __builtin_amdgcn_mfma_f32_16x16x32_f16(v, pb[1][s], Oacc[1][ft], 0, 0, 0);
            }
    }
#pragma unroll
    for (int sub = 0; sub < 2; sub++) {
#pragma unroll
        for (int ft = 0; ft < 4; ft++) {
            half4 o;
#pragma unroll
            for (int r = 0; r < 4; r++) o[r] = (_Float16)Oacc[sub][ft][r];
            *(half4*)(Op + ((size_t)sp * NPTS + q0w + sub * 16 + qi) * 64 + ft * 16 + quad * 4) = o;
        }
        if (lane < 16) {
            Ms[sp * NPTS + q0w + sub * 16 + lane] = m_i[sub];
            Ls[sp * NPTS + q0w + sub * 16 + lane] = l_i[sub];
        }
    }
}

// ---------------- combine 8 key-split partials (fp16 partials) ----------------
__global__ __launch_bounds__(256) void merge1(const _Float16* __restrict__ Op, const float* __restrict__ Ms,
                                              const float* __restrict__ Ls, float* __restrict__ xr) {
    int i = blockIdx.x * 256 + threadIdx.x;
    int q = i >> 4, f4 = (i & 15) * 4;
    float m[8], M = -1e30f;
#pragma unroll
    for (int s = 0; s < 8; s++) {
        m[s] = Ms[s * NPTS + q];
        M = fmaxf(M, m[s]);
    }
    float L = 0.f;
    float4 acc = {0.f, 0.f, 0.f, 0.f};
#pragma unroll
    for (int s = 0; s < 8; s++) {
        float w = __expf(m[s] - M);
        L += Ls[s * NPTS + q] * w;
        half4 o = *(const half4*)(Op + ((size_t)s * NPTS + q) * 64 + f4);
        acc.x += (float)o[0] * w;
        acc.y += (float)o[1] * w;
        acc.z += (float)o[2] * w;
        acc.w += (float)o[3] * w;
    }
    float inv = 1.f / L;
    float4 r = {acc.x * inv, acc.y * inv, acc.z * inv, acc.w * inv};
    *(float4*)(xr + q * 64 + f4) = r;
}

// ---------------- Stage-2 ragged flash attention, MFMA, LDS-staged (R4 version) ----------
__global__ __launch_bounds__(256) void flash2_mfma(const _Float16* __restrict__ Qh,
                                                   const _Float16* __restrict__ Ql,
                                                   const _Float16* __restrict__ Kh,
                                                   const _Float16* __restrict__ Vt2,
                                                   const int* __restrict__ pad_idx,
                                                   const int* __restrict__ counts,
                                                   _Float16* __restrict__ O) {
    int b = blockIdx.y;
    int c = counts[b];
    int qb = blockIdx.x;
    if (qb * 64 >= c) return;
    __shared__ __align__(16) _Float16 KsF[8 * 512];
    __shared__ __align__(16) _Float16 VsF[8 * 512];
    __shared__ __align__(16) _Float16 PTF[4][2 * 512];
    int t = threadIdx.x;
    int lane = t & 63, wv = t >> 6;
    int quad = lane >> 4, qi = lane & 15;
    const int* prow = pad_idx + b * LQPAD;
    int p_q = qb * 64 + wv * 16 + qi;
    int flat_q = (p_q < LQPAD) ? prow[p_q] : -1;

    half8 qh[2], ql[2];
#pragma unroll
    for (int s = 0; s < 2; s++) {
        if (flat_q >= 0) {
            qh[s] = *(const half8*)(Qh + (size_t)flat_q * 64 + s * 32 + quad * 8);
            ql[s] = *(const half8*)(Ql + (size_t)flat_q * 64 + s * 32 + quad * 8);
        } else {
            qh[s] = half8{0, 0, 0, 0, 0, 0, 0, 0};
            ql[s] = half8{0, 0, 0, 0, 0, 0, 0, 0};
        }
    }
    floatx4 Oacc[4];
#pragma unroll
    for (int ft = 0; ft < 4; ft++) Oacc[ft] = floatx4{0.f, 0.f, 0.f, 0.f};
    float m_i = -1e30f, l_i = 0.f;
    const _Float16* VtB = Vt2 + (size_t)b * 64 * LPAD2;

    int nt = (c + 63) >> 6;
    for (int it = 0; it < nt; it++) {
        int k0 = it * 64;
        __syncthreads();
#pragma unroll
        for (int u = 0; u < 4; u++) {
            int frag = wv + 4 * u;
            if (frag < 8) {
                int kt = frag >> 1, s = frag & 1;
                int kp = k0 + kt * 16 + qi;
                int flat = (kp < c) ? prow[kp] : -1;
                int d0 = s * 32 + quad * 8;
                half8 kvv = half8{0, 0, 0, 0, 0, 0, 0, 0};
                if (flat >= 0) kvv = *(const half8*)(Kh + (size_t)flat * 64 + d0);
                *(half8*)(KsF + frag * 512 + lane * 8) = kvv;
            } else {
                int fr = frag - 8;
                int ft = fr >> 1, s = fr & 1;
                int f = ft * 16 + qi;
                int key = k0 + s * 32 + quad * 8;
                *(half8*)(VsF + fr * 512 + lane * 8) = *(const half8*)(VtB + f * LPAD2 + key);
            }
        }
        __syncthreads();
        floatx4 st[4];
#pragma unroll
        for (int kt = 0; kt < 4; kt++) {
            floatx4 acc = floatx4{0.f, 0.f, 0.f, 0.f};
#pragma unroll
            for (int s = 0; s < 2; s++) {
                half8 a = *(const half8*)(KsF + (kt * 2 + s) * 512 + lane * 8);
                acc = __builtin_amdgcn_mfma_f32_16x16x32_f16(a, qh[s], acc, 0, 0, 0);
                acc = __builtin_amdgcn_mfma_f32_16x16x32_f16(a, ql[s], acc, 0, 0, 0);
            }
            st[kt] = acc;
        }
        float mloc = -1e30f;
#pragma unroll
        for (int kt = 0; kt < 4; kt++)
#pragma unroll
            for (int r = 0; r < 4; r++) mloc = fmaxf(mloc, st[kt][r]);
        mloc = fmaxf(mloc, __shfl_xor(mloc, 16));
        mloc = fmaxf(mloc, __shfl_xor(mloc, 32));
        float m_new = fmaxf(m_i, mloc);
        float alpha = __expf(m_i - m_new);
        float ps = 0.f;
#pragma unroll
        for (int kt = 0; kt < 4; kt++) {
            half4 pk;
#pragma unroll
            for (int r = 0; r < 4; r++) {
                int kpos = k0 + kt * 16 + quad * 4 + r;
                float p = (kpos < c) ? __expf(st[kt][r] - m_new) : 0.f;
                ps += p;
                pk[r] = (_Float16)p;
            }
            int s = kt >> 1;
            int qd2 = (kt & 1) * 2 + (quad >> 1);
            *(half4*)(&PTF[wv][(s * 64 + qd2 * 16 + qi) * 8 + (quad & 1) * 4]) = pk;
        }
        ps += __shfl_xor(ps, 16);
        ps += __shfl_xor(ps, 32);
        l_i = l_i * alpha + ps;
        m_i = m_new;
#pragma unroll
        for (int ft = 0; ft < 4; ft++) Oacc[ft] *= alpha;
        half8 pb[2];
#pragma unroll
        for (int s = 0; s < 2; s++) pb[s] = *(const half8*)(&PTF[wv][(s * 64 + lane) * 8]);
#pragma unroll
        for (int ft = 0; ft < 4; ft++)
#pragma unroll
            for (int s = 0; s < 2; s++) {
                half8 a = *(const half8*)(VsF + (ft * 2 + s) * 512 + lane * 8);
                Oacc[ft] = __builtin_amdgcn_mfma_f32_16x16x32_f16(a, pb[s], Oacc[ft], 0, 0, 0);
            }
    }
    if (flat_q >= 0) {
        float inv = 1.f / l_i;
#pragma unroll
        for (int ft = 0; ft < 4; ft++) {
            half4 o;
#pragma unroll
            for (int r = 0; r < 4; r++) o[r] = (_Float16)(Oacc[ft][r] * inv);
            *(half4*)(O + (size_t)flat_q * 64 + ft * 16 + quad * 4) = o;
        }
    }
}

extern "C" void kernel_launch(void* const* d_in, const int* in_sizes, int n_in,
                              void* d_out, int out_size, void* d_ws, size_t ws_size,
                              hipStream_t stream) {
    const float* x_dec = (const float*)d_in[0];
    const float* x_enc = (const float*)d_in[1];
    const float* Wp1 = (const float*)d_in[2];
    const float* Wq = (const float*)d_in[3];
    const float* Wk = (const float*)d_in[4];
    const float* Wv = (const float*)d_in[5];
    const float* Wt_ = (const float*)d_in[6];
    const float* Wq1 = (const float*)d_in[7];
    const float* Wk1 = (const float*)d_in[8];
    const float* Wv1 = (const float*)d_in[9];
    const float* Wdown = (const float*)d_in[10];
    const float* W3t = (const float*)d_in[11];
    const float* W3a = (const float*)d_in[12];
    const float* W3b = (const float*)d_in[13];
    const float* bn_g = (const float*)d_in[14];
    const float* bn_b = (const float*)d_in[15];
    const int* nbr = (const int*)d_in[16];
    const int* kv_nbr = (const int*)d_in[17];
    const int* pad_idx = (const int*)d_in[18];
    float* out = (float*)d_out;
    float* ws = (float*)d_ws;

    const int N = NPTS;
    const size_t BUF = (size_t)N * 64;
    float* xd = ws;
    float* q = ws + BUF;
    float* ke = ws + 2 * BUF;
    float* ve = ws + 3 * BUF;
    float* xr = ws + 4 * BUF;
    float* kv = ws + 5 * BUF;
    float* o2 = ws + 6 * BUF;
    float* xr2 = ws + 7 * BUF;
    float* z2 = ws + 8 * BUF;
    float* stats = ws + 9 * BUF;
    int* counts = (int*)(stats + 768);
    float* Ms = stats + 1024;          // 8 * NPTS
    float* Ls = Ms + 8 * NPTS;         // 8 * NPTS

    _Float16* Oph = (_Float16*)q;      // fp16 partials: 8*NPTS*64*2B = slots 1..4 exactly
    _Float16* Qh = (_Float16*)kv;
    _Float16* Ql = Qh + BUF;
    _Float16* Kh = (_Float16*)o2;
    _Float16* Vt = Kh + BUF;
    _Float16* Qh1 = (_Float16*)kv;
    _Float16* Ql1 = Qh1 + BUF;
    _Float16* Kh1 = (_Float16*)o2;
    _Float16* Vt2 = (_Float16*)xr;
    _Float16* q1h = (_Float16*)xr;
    _Float16* z2h = (_Float16*)z2;
    _Float16* Wf_dt = z2h + BUF;
    _Float16* Wf_d = Wf_dt;
    _Float16* Wf_3t = Wf_dt + (size_t)8 * 4096;
    _Float16* xrh = (_Float16*)xr;
    _Float16* xr2h = (_Float16*)xr2;
    _Float16* Wf_ab = (_Float16*)kv;
    _Float16* Wf_3a = Wf_ab;
    _Float16* Wf_3b = Wf_ab + (size_t)27 * 4096;

    hipMemsetAsync(stats, 0, 1024 * sizeof(float), stream);

    dim3 B(256);
    int gR = N / 16;
    int gC = N / 64;
    int gS = 64;
    int gE = (N * 64) / 256;

    pack_w<<<8, B, 0, stream>>>(Wdown, Wf_d);
    pack_w<<<27, B, 0, stream>>>(W3t, Wf_3t);

    gemm64<<<gR, B, 0, stream>>>(x_dec, Wp1, xd, nullptr, N);
    gemm64<<<gR, B, 0, stream>>>(xd, Wq, q, nullptr, N);
    gemm64<<<gR, B, 0, stream>>>(x_enc, Wk, ke, nullptr, N);
    gemm64<<<gR, B, 0, stream>>>(x_enc, Wv, ve, nullptr, N);
    prep_split<<<gE, B, 0, stream>>>(q, ke, Qh, Ql, Kh);
    vtrans<<<N / 64, B, 0, stream>>>(ve, Vt);
    // q/ke/ve fp32 now dead -> slots 1..4 become fp16 partial buffer Oph
    flash1_mfma<<<dim3(N / 128, 8), B, 0, stream>>>(Qh, Ql, Kh, Vt, Oph, Ms, Ls);
    merge1<<<(N * 16) / 256, B, 0, stream>>>(Oph, Ms, Ls, xr2);  // out to slot 7 (slot 4 holds partials)
    gemm64<<<gR, B, 0, stream>>>(xr2, Wt_, xr, nullptr, N);
    bn_stats<<<gS, B, 0, stream>>>(xr, nullptr, stats + 0, N);
    bn_apply<<<gE, B, 0, stream>>>(xr, nullptr, xd, xd, nullptr, stats + 0, bn_g + 0, bn_b + 0, N, 0);

    gemm64<<<gR, B, 0, stream>>>(xd, Wq1, q, q1h, N);
    gconv_mfma<<<gC, B, 0, stream>>>(q1h, kv_nbr, Wf_d, kv, 8);
    bn_stats<<<gS, B, 0, stream>>>(kv, nullptr, stats + 128, N);
    bn_apply<<<gE, B, 0, stream>>>(kv, nullptr, nullptr, kv, nullptr, stats + 128, bn_g + 64, bn_b + 64, N, 0);
    gemm64<<<gR, B, 0, stream>>>(kv, Wk1, ke, nullptr, N);
    gemm64<<<gR, B, 0, stream>>>(kv, Wv1, ve, nullptr, N);
    prep_split<<<gE, B, 0, stream>>>(q, ke, Qh1, Ql1, Kh1);
    vtrans2<<<dim3(LPAD2 / 64, 8), B, 0, stream>>>(ve, pad_idx, Vt2);
    count_valid<<<8, B, 0, stream>>>(pad_idx, counts);
    flash2_mfma<<<dim3(LPAD2 / 64, 8), B, 0, stream>>>(Qh1, Ql1, Kh1, Vt2, pad_idx, counts, z2h);
    pack_w<<<27, B, 0, stream>>>(W3a, Wf_3a);
    pack_w<<<27, B, 0, stream>>>(W3b, Wf_3b);
    gconv_mfma<<<gC, B, 0, stream>>>(z2h, nbr, Wf_3t, xr2, 27);
    bn_stats<<<gS, B, 0, stream>>>(xr2, nullptr, stats + 256, N);
    bn_apply<<<gE, B, 0, stream>>>(xr2, nullptr, xd, xd, nullptr, stats + 256, bn_g + 128, bn_b + 128, N, 0);

    bn_stats<<<gS, B, 0, stream>>>(xd, nullptr, stats + 384, N);
    bn_apply<<<gE, B, 0, stream>>>(xd, nullptr, nullptr, nullptr, xrh, stats + 384, bn_g + 192, bn_b + 192, N, 1);
    gconv_mfma<<<gC, B, 0, stream>>>(xrh, nbr, Wf_3a, o2, 27);
    bn_stats<<<gS, B, 0, stream>>>(o2, nullptr, stats + 512, N);
    bn_apply<<<gE, B, 0, stream>>>(o2, nullptr, nullptr, nullptr, xr2h, stats + 512, bn_g + 256, bn_b + 256, N, 1);
    gconv_mfma<<<gC, B, 0, stream>>>(xr2h, nbr, Wf_3b, z2, 27);
    bn_stats<<<gS, B, 0, stream>>>(xd, z2, stats + 640, N);
    bn_apply<<<gE, B, 0, stream>>>(xd, z2, nullptr, out, nullptr, stats + 640, bn_g + 320, bn_b + 320, N, 1);
}

// Round 7
// 433.611 us; speedup vs baseline: 1.6557x; 1.2625x over previous
//
#include <hip/hip_runtime.h>

#define NPTS 12288
#define LQPAD 1800
#define LPAD2 1856
#define EPSBN 1e-4f

typedef _Float16 half8 __attribute__((ext_vector_type(8)));
typedef _Float16 half4 __attribute__((ext_vector_type(4)));
typedef float floatx4 __attribute__((ext_vector_type(4)));

// ---------------- Wpq = Wp1 @ Wq (fp32, one block) ----------------
__global__ __launch_bounds__(256) void wprod(const float* __restrict__ Wp1, const float* __restrict__ Wq,
                                             float* __restrict__ Wpq) {
    __shared__ float A[4096], Bs[4096];
    int t = threadIdx.x;
    for (int i = t; i < 4096; i += 256) {
        A[i] = Wp1[i];
        Bs[i] = Wq[i];
    }
    __syncthreads();
    for (int o = 0; o < 16; o++) {
        int idx = o * 256 + t;
        int i = idx >> 6, j = idx & 63;
        float s = 0.f;
#pragma unroll
        for (int k = 0; k < 64; k++) s += A[i * 64 + k] * Bs[k * 64 + j];
        Wpq[idx] = s;
    }
}

// ---------------- pack ALL weights into B-fragment-major fp16 arena ----------------
// arena tap g: 0 Wp1, 1 Wpq, 2 Wk, 3 Wv, 4 Wt, 5 Wq1, 6 Wk1, 7 Wv1,
// 8..15 Wdown, 16..42 W3t, 43..69 W3a, 70..96 W3b
__global__ __launch_bounds__(256) void pack_all(const float* Wp1, const float* Wpq, const float* Wk,
                                                const float* Wv, const float* Wt_, const float* Wq1,
                                                const float* Wk1, const float* Wv1, const float* Wdown,
                                                const float* W3t, const float* W3a, const float* W3b,
                                                _Float16* __restrict__ Wf) {
    int g = blockIdx.x;
    const float* src;
    if (g == 0) src = Wp1;
    else if (g == 1) src = Wpq;
    else if (g == 2) src = Wk;
    else if (g == 3) src = Wv;
    else if (g == 4) src = Wt_;
    else if (g == 5) src = Wq1;
    else if (g == 6) src = Wk1;
    else if (g == 7) src = Wv1;
    else if (g < 16) src = Wdown + (size_t)(g - 8) * 4096;
    else if (g < 43) src = W3t + (size_t)(g - 16) * 4096;
    else if (g < 70) src = W3a + (size_t)(g - 43) * 4096;
    else src = W3b + (size_t)(g - 70) * 4096;
    int t = threadIdx.x;
    int lane = t & 63, fg = t >> 6;
    int quad = lane >> 4, qi = lane & 15;
#pragma unroll
    for (int u = 0; u < 2; u++) {
        int frag = fg * 2 + u;
        int s = frag >> 2, ct = frag & 3;
        half8 v;
#pragma unroll
        for (int j = 0; j < 8; j++) v[j] = (_Float16)src[(s * 32 + quad * 8 + j) * 64 + ct * 16 + qi];
        *(half8*)(Wf + (size_t)g * 4096 + frag * 512 + lane * 8) = v;
    }
}

// A fp32 row -> hi/lo half8 fragments
__device__ inline void load_split8(const float* p, half8& hi, half8& lo) {
    float4 a = *(const float4*)p;
    float4 b = *(const float4*)(p + 4);
    float v[8] = {a.x, a.y, a.z, a.w, b.x, b.y, b.z, b.w};
#pragma unroll
    for (int j = 0; j < 8; j++) {
        _Float16 h = (_Float16)v[j];
        hi[j] = h;
        lo[j] = (_Float16)(v[j] - (float)h);
    }
}

// ---------------- gemm_head: 4 GEMMs in one launch (stage-1 inputs) ----------------
// y=0: xd = x_dec@Wp1 (fp32)  y=1: q = x_dec@Wpq (Qh/Ql split)
// y=2: ke = x_enc@Wk (Kh fp16)  y=3: ve = x_enc@Wv (Vt transposed fp16)
__global__ __launch_bounds__(256) void gemm_head(const float* __restrict__ xdec, const float* __restrict__ xenc,
                                                 const _Float16* __restrict__ Wf, float* __restrict__ xd,
                                                 _Float16* __restrict__ Qh, _Float16* __restrict__ Ql,
                                                 _Float16* __restrict__ Kh, _Float16* __restrict__ Vt) {
    int z = blockIdx.y;
    const float* A = (z < 2) ? xdec : xenc;
    const _Float16* Bf = Wf + (size_t)z * 4096;
    int t = threadIdx.x;
    int lane = t & 63, wv = t >> 6;
    int quad = lane >> 4, qi = lane & 15;
    int row0w = blockIdx.x * 64 + wv * 16;
    half8 ah[2], al[2];
#pragma unroll
    for (int s = 0; s < 2; s++) load_split8(A + (size_t)(row0w + qi) * 64 + s * 32 + quad * 8, ah[s], al[s]);
    floatx4 C[4];
#pragma unroll
    for (int ct = 0; ct < 4; ct++) C[ct] = floatx4{0.f, 0.f, 0.f, 0.f};
#pragma unroll
    for (int ct = 0; ct < 4; ct++)
#pragma unroll
        for (int s = 0; s < 2; s++) {
            half8 b = *(const half8*)(Bf + (s * 4 + ct) * 512 + lane * 8);
            C[ct] = __builtin_amdgcn_mfma_f32_16x16x32_f16(ah[s], b, C[ct], 0, 0, 0);
            C[ct] = __builtin_amdgcn_mfma_f32_16x16x32_f16(al[s], b, C[ct], 0, 0, 0);
        }
    int orow = row0w + quad * 4;
    if (z == 0) {
#pragma unroll
        for (int ct = 0; ct < 4; ct++)
#pragma unroll
            for (int r = 0; r < 4; r++) xd[(size_t)(orow + r) * 64 + ct * 16 + qi] = C[ct][r];
    } else if (z == 1) {
#pragma unroll
        for (int ct = 0; ct < 4; ct++)
#pragma unroll
            for (int r = 0; r < 4; r++) {
                float v = C[ct][r];
                _Float16 h = (_Float16)v;
                Qh[(size_t)(orow + r) * 64 + ct * 16 + qi] = h;
                Ql[(size_t)(orow + r) * 64 + ct * 16 + qi] = (_Float16)(v - (float)h);
            }
    } else if (z == 2) {
#pragma unroll
        for (int ct = 0; ct < 4; ct++)
#pragma unroll
            for (int r = 0; r < 4; r++) Kh[(size_t)(orow + r) * 64 + ct * 16 + qi] = (_Float16)C[ct][r];
    } else {
#pragma unroll
        for (int ct = 0; ct < 4; ct++) {
            half4 o;
#pragma unroll
            for (int r = 0; r < 4; r++) o[r] = (_Float16)C[ct][r];
            *(half4*)(Vt + (size_t)(ct * 16 + qi) * NPTS + orow) = o;
        }
    }
}

// ---------------- gemm -> hi/lo split output (q1) ----------------
__global__ __launch_bounds__(256) void gemm_split(const float* __restrict__ A, const _Float16* __restrict__ Bf,
                                                  _Float16* __restrict__ Oh, _Float16* __restrict__ Ol) {
    int t = threadIdx.x;
    int lane = t & 63, wv = t >> 6;
    int quad = lane >> 4, qi = lane & 15;
    int row0w = blockIdx.x * 64 + wv * 16;
    half8 ah[2], al[2];
#pragma unroll
    for (int s = 0; s < 2; s++) load_split8(A + (size_t)(row0w + qi) * 64 + s * 32 + quad * 8, ah[s], al[s]);
    floatx4 C[4];
#pragma unroll
    for (int ct = 0; ct < 4; ct++) C[ct] = floatx4{0.f, 0.f, 0.f, 0.f};
#pragma unroll
    for (int ct = 0; ct < 4; ct++)
#pragma unroll
        for (int s = 0; s < 2; s++) {
            half8 b = *(const half8*)(Bf + (s * 4 + ct) * 512 + lane * 8);
            C[ct] = __builtin_amdgcn_mfma_f32_16x16x32_f16(ah[s], b, C[ct], 0, 0, 0);
            C[ct] = __builtin_amdgcn_mfma_f32_16x16x32_f16(al[s], b, C[ct], 0, 0, 0);
        }
    int orow = row0w + quad * 4;
#pragma unroll
    for (int ct = 0; ct < 4; ct++)
#pragma unroll
        for (int r = 0; r < 4; r++) {
            float v = C[ct][r];
            _Float16 h = (_Float16)v;
            Oh[(size_t)(orow + r) * 64 + ct * 16 + qi] = h;
            Ol[(size_t)(orow + r) * 64 + ct * 16 + qi] = (_Float16)(v - (float)h);
        }
}

// ---------------- gemm_kv1: BN(kv) fused prologue; y=0 -> Kh1, y=1 -> Vt2 scatter ---------
__global__ __launch_bounds__(256) void gemm_kv1(const float* __restrict__ kv, const _Float16* __restrict__ Wfk,
                                                const _Float16* __restrict__ Wfv,
                                                const float* __restrict__ stats, const float* __restrict__ gamma,
                                                const float* __restrict__ beta, const int* __restrict__ unpad,
                                                _Float16* __restrict__ Kh1, _Float16* __restrict__ Vt2) {
    int y = blockIdx.y;
    int t = threadIdx.x;
    int lane = t & 63, wv = t >> 6;
    int quad = lane >> 4, qi = lane & 15;
    int row0w = blockIdx.x * 64 + wv * 16;
    const float inv_n = 1.f / (float)NPTS;
    half8 ah[2], al[2];
#pragma unroll
    for (int s = 0; s < 2; s++) {
        const float* p = kv + (size_t)(row0w + qi) * 64 + s * 32 + quad * 8;
        float4 a = *(const float4*)p;
        float4 b2 = *(const float4*)(p + 4);
        float v[8] = {a.x, a.y, a.z, a.w, b2.x, b2.y, b2.z, b2.w};
#pragma unroll
        for (int j = 0; j < 8; j++) {
            int f = s * 32 + quad * 8 + j;
            float mean = stats[f] * inv_n;
            float var = stats[64 + f] * inv_n - mean * mean;
            float val = (v[j] - mean) * rsqrtf(var + EPSBN) * gamma[f] + beta[f];
            _Float16 h = (_Float16)val;
            ah[s][j] = h;
            al[s][j] = (_Float16)(val - (float)h);
        }
    }
    const _Float16* Bf = y ? Wfv : Wfk;
    floatx4 C[4];
#pragma unroll
    for (int ct = 0; ct < 4; ct++) C[ct] = floatx4{0.f, 0.f, 0.f, 0.f};
#pragma unroll
    for (int ct = 0; ct < 4; ct++)
#pragma unroll
        for (int s = 0; s < 2; s++) {
            half8 b = *(const half8*)(Bf + (s * 4 + ct) * 512 + lane * 8);
            C[ct] = __builtin_amdgcn_mfma_f32_16x16x32_f16(ah[s], b, C[ct], 0, 0, 0);
            C[ct] = __builtin_amdgcn_mfma_f32_16x16x32_f16(al[s], b, C[ct], 0, 0, 0);
        }
    int orow = row0w + quad * 4;
    if (y == 0) {
#pragma unroll
        for (int ct = 0; ct < 4; ct++)
#pragma unroll
            for (int r = 0; r < 4; r++) Kh1[(size_t)(orow + r) * 64 + ct * 16 + qi] = (_Float16)C[ct][r];
    } else {
        int u0 = unpad[orow], u3 = unpad[orow + 3];
        int b0 = u0 / 1800, b3 = u3 / 1800;
        if (u3 == u0 + 3 && b0 == b3) {
            int p0 = u0 - b0 * 1800;
#pragma unroll
            for (int ct = 0; ct < 4; ct++) {
                half4 o;
#pragma unroll
                for (int r = 0; r < 4; r++) o[r] = (_Float16)C[ct][r];
                *(half4*)(Vt2 + ((size_t)b0 * 64 + ct * 16 + qi) * LPAD2 + p0) = o;
            }
        } else {
#pragma unroll
            for (int r = 0; r < 4; r++) {
                int u = unpad[orow + r];
                int b = u / 1800, p = u - b * 1800;
#pragma unroll
                for (int ct = 0; ct < 4; ct++)
                    Vt2[((size_t)b * 64 + ct * 16 + qi) * LPAD2 + p] = (_Float16)C[ct][r];
            }
        }
    }
}

// ---------------- gather conv, MFMA, optional fused BN-stats ----------------
__global__ __launch_bounds__(256) void gconv_mfma(const _Float16* __restrict__ Xh,
                                                  const int* __restrict__ idx,
                                                  const _Float16* __restrict__ Wf,
                                                  float* __restrict__ OUT, int nk,
                                                  const float* Xadd, float* stats_out) {
    __shared__ float s_sum[64], s_ss[64];
    int t = threadIdx.x;
    int lane = t & 63, wv = t >> 6;
    int quad = lane >> 4, qi = lane & 15;
    int row0 = blockIdx.x * 64 + wv * 16;
    if (stats_out) {
        if (t < 64) {
            s_sum[t] = 0.f;
            s_ss[t] = 0.f;
        }
        __syncthreads();
    }
    floatx4 Oacc[4];
#pragma unroll
    for (int ct = 0; ct < 4; ct++) Oacc[ct] = floatx4{0.f, 0.f, 0.f, 0.f};
    const int* ip = idx + (size_t)(row0 + qi) * nk;
    for (int k = 0; k < nk; k++) {
        int j = ip[k];
        half8 a0 = half8{0, 0, 0, 0, 0, 0, 0, 0};
        half8 a1 = half8{0, 0, 0, 0, 0, 0, 0, 0};
        if (j >= 0) {
            a0 = *(const half8*)(Xh + (size_t)j * 64 + quad * 8);
            a1 = *(const half8*)(Xh + (size_t)j * 64 + 32 + quad * 8);
        }
        const _Float16* wk = Wf + (size_t)k * 4096;
#pragma unroll
        for (int ct = 0; ct < 4; ct++) {
            half8 b0 = *(const half8*)(wk + ct * 512 + lane * 8);
            half8 b1 = *(const half8*)(wk + (4 + ct) * 512 + lane * 8);
            Oacc[ct] = __builtin_amdgcn_mfma_f32_16x16x32_f16(a0, b0, Oacc[ct], 0, 0, 0);
            Oacc[ct] = __builtin_amdgcn_mfma_f32_16x16x32_f16(a1, b1, Oacc[ct], 0, 0, 0);
        }
    }
    int orow = row0 + quad * 4;
#pragma unroll
    for (int ct = 0; ct < 4; ct++)
#pragma unroll
        for (int r = 0; r < 4; r++) OUT[(size_t)(orow + r) * 64 + ct * 16 + qi] = Oacc[ct][r];
    if (stats_out) {
#pragma unroll
        for (int ct = 0; ct < 4; ct++) {
            int f = ct * 16 + qi;
            float ps = 0.f, pss = 0.f;
#pragma unroll
            for (int r = 0; r < 4; r++) {
                float v = Oacc[ct][r];
                if (Xadd) v += Xadd[(size_t)(orow + r) * 64 + f];
                ps += v;
                pss += v * v;
            }
            atomicAdd(&s_sum[f], ps);
            atomicAdd(&s_ss[f], pss);
        }
        __syncthreads();
        if (t < 64) {
            atomicAdd(&stats_out[t], s_sum[t]);
            atomicAdd(&stats_out[64 + t], s_ss[t]);
        }
    }
}

// ---------------- bn_apply (grid-strided, optional fp32/fp16 out, optional stats-out) ------
__global__ __launch_bounds__(256) void bn_apply(const float* __restrict__ X, const float* X2,
                                                const float* R, float* OUT, _Float16* OUT16,
                                                const float* __restrict__ stats,
                                                const float* __restrict__ gamma,
                                                const float* __restrict__ beta,
                                                float* stats_out, int n, int do_relu) {
    __shared__ float sh[2][4][64];
    int t = threadIdx.x;
    int f = t & 63, g = t >> 6;
    float inv_n = 1.f / (float)n;
    float mean = stats[f] * inv_n;
    float var = stats[64 + f] * inv_n - mean * mean;
    float rstd = rsqrtf(var + EPSBN);
    float ga = gamma[f], be = beta[f];
    float s = 0.f, ss = 0.f;
    for (int r = blockIdx.x * 4 + g; r < n; r += gridDim.x * 4) {
        size_t i = (size_t)r * 64 + f;
        float v = X[i];
        if (X2) v += X2[i];
        v = (v - mean) * rstd * ga + be;
        if (R) v += R[i];
        if (do_relu) v = fmaxf(v, 0.f);
        if (OUT) OUT[i] = v;
        if (OUT16) OUT16[i] = (_Float16)v;
        s += v;
        ss += v * v;
    }
    if (stats_out) {
        sh[0][g][f] = s;
        sh[1][g][f] = ss;
        __syncthreads();
        if (g == 0) {
            s = sh[0][0][f] + sh[0][1][f] + sh[0][2][f] + sh[0][3][f];
            ss = sh[1][0][f] + sh[1][1][f] + sh[1][2][f] + sh[1][3][f];
            atomicAdd(&stats_out[f], s);
            atomicAdd(&stats_out[64 + f], ss);
        }
    }
}

// ---------------- per-batch valid counts ----------------
__global__ __launch_bounds__(256) void count_valid(const int* __restrict__ pad_idx, int* __restrict__ counts) {
    int b = blockIdx.x;
    int t = threadIdx.x;
    int s = 0;
    for (int i = t; i < LQPAD; i += 256) s += (pad_idx[b * LQPAD + i] >= 0) ? 1 : 0;
    for (int off = 32; off > 0; off >>= 1) s += __shfl_xor(s, off);
    if ((t & 63) == 0) atomicAdd(&counts[b], s);
}

// ---------------- Stage-1 flash attention (R6 version, unchanged) ----------------
__global__ __launch_bounds__(256, 3) void flash1_mfma(const _Float16* __restrict__ Qh,
                                                      const _Float16* __restrict__ Ql,
                                                      const _Float16* __restrict__ Kh,
                                                      const _Float16* __restrict__ Vt,
                                                      _Float16* __restrict__ Op,
                                                      float* __restrict__ Ms,
                                                      float* __restrict__ Ls) {
    __shared__ __align__(16) _Float16 KsF[8 * 512];
    __shared__ __align__(16) _Float16 VsF[8 * 512];
    __shared__ __align__(16) _Float16 PTF[4][2 * 1024];
    int t = threadIdx.x;
    int lane = t & 63, wv = t >> 6;
    int quad = lane >> 4, qi = lane & 15;
    int qb = blockIdx.x, sp = blockIdx.y;
    int q0w = qb * 128 + wv * 32;

    half8 qh[2][2], ql[2][2];
#pragma unroll
    for (int sub = 0; sub < 2; sub++)
#pragma unroll
        for (int s = 0; s < 2; s++) {
            int qrow = q0w + sub * 16 + qi;
            qh[sub][s] = *(const half8*)(Qh + (size_t)qrow * 64 + s * 32 + quad * 8);
            ql[sub][s] = *(const half8*)(Ql + (size_t)qrow * 64 + s * 32 + quad * 8);
        }
    floatx4 Oacc[2][4];
#pragma unroll
    for (int sub = 0; sub < 2; sub++)
#pragma unroll
        for (int ft = 0; ft < 4; ft++) Oacc[sub][ft] = floatx4{0.f, 0.f, 0.f, 0.f};
    float m_i[2] = {-1e30f, -1e30f}, l_i[2] = {0.f, 0.f};

    for (int it = 0; it < 24; it++) {
        int k0 = sp * 1536 + it * 64;
        __syncthreads();
#pragma unroll
        for (int u = 0; u < 4; u++) {
            int frag = wv + 4 * u;
            if (frag < 8) {
                int kt = frag >> 1, s = frag & 1;
                int key = k0 + kt * 16 + qi;
                *(half8*)(KsF + frag * 512 + lane * 8) =
                    *(const half8*)(Kh + (size_t)key * 64 + s * 32 + quad * 8);
            } else {
                int fr = frag - 8;
                int ft = fr >> 1, s = fr & 1;
                int f = ft * 16 + qi;
                *(half8*)(VsF + fr * 512 + lane * 8) =
                    *(const half8*)(Vt + (size_t)f * NPTS + k0 + s * 32 + quad * 8);
            }
        }
        __syncthreads();
        half8 ka[4][2];
#pragma unroll
        for (int kt = 0; kt < 4; kt++)
#pragma unroll
            for (int s = 0; s < 2; s++) ka[kt][s] = *(const half8*)(KsF + (kt * 2 + s) * 512 + lane * 8);
        floatx4 st[2][4];
#pragma unroll
        for (int sub = 0; sub < 2; sub++)
#pragma unroll
            for (int kt = 0; kt < 4; kt++) {
                floatx4 acc = floatx4{0.f, 0.f, 0.f, 0.f};
#pragma unroll
                for (int s = 0; s < 2; s++) {
                    acc = __builtin_amdgcn_mfma_f32_16x16x32_f16(ka[kt][s], qh[sub][s], acc, 0, 0, 0);
                    acc = __builtin_amdgcn_mfma_f32_16x16x32_f16(ka[kt][s], ql[sub][s], acc, 0, 0, 0);
                }
                st[sub][kt] = acc;
            }
#pragma unroll
        for (int sub = 0; sub < 2; sub++) {
            float mloc = -1e30f;
#pragma unroll
            for (int kt = 0; kt < 4; kt++)
#pragma unroll
                for (int r = 0; r < 4; r++) mloc = fmaxf(mloc, st[sub][kt][r]);
            mloc = fmaxf(mloc, __shfl_xor(mloc, 16));
            mloc = fmaxf(mloc, __shfl_xor(mloc, 32));
            float m_new = fmaxf(m_i[sub], mloc);
            float alpha = __expf(m_i[sub] - m_new);
            float ps = 0.f;
#pragma unroll
            for (int kt = 0; kt < 4; kt++) {
                half4 pk;
#pragma unroll
                for (int r = 0; r < 4; r++) {
                    float p = __expf(st[sub][kt][r] - m_new);
                    ps += p;
                    pk[r] = (_Float16)p;
                }
                int s = kt >> 1;
                int qd2 = (kt & 1) * 2 + (quad >> 1);
                *(half4*)(&PTF[wv][sub * 1024 + (s * 64 + qd2 * 16 + qi) * 8 + (quad & 1) * 4]) = pk;
            }
            ps += __shfl_xor(ps, 16);
            ps += __shfl_xor(ps, 32);
            l_i[sub] = l_i[sub] * alpha + ps;
            m_i[sub] = m_new;
#pragma unroll
            for (int ft = 0; ft < 4; ft++) Oacc[sub][ft] *= alpha;
        }
        half8 pb[2][2];
#pragma unroll
        for (int sub = 0; sub < 2; sub++)
#pragma unroll
            for (int s = 0; s < 2; s++)
                pb[sub][s] = *(const half8*)(&PTF[wv][sub * 1024 + (s * 64 + lane) * 8]);
#pragma unroll
        for (int ft = 0; ft < 4; ft++)
#pragma unroll
            for (int s = 0; s < 2; s++) {
                half8 v = *(const half8*)(VsF + (ft * 2 + s) * 512 + lane * 8);
                Oacc[0][ft] = __builtin_amdgcn_mfma_f32_16x16x32_f16(v, pb[0][s], Oacc[0][ft], 0, 0, 0);
                Oacc[1][ft] = __builtin_amdgcn_mfma_f32_16x16x32_f16(v, pb[1][s], Oacc[1][ft], 0, 0, 0);
            }
    }
#pragma unroll
    for (int sub = 0; sub < 2; sub++) {
#pragma unroll
        for (int ft = 0; ft < 4; ft++) {
            half4 o;
#pragma unroll
            for (int r = 0; r < 4; r++) o[r] = (_Float16)Oacc[sub][ft][r];
            *(half4*)(Op + ((size_t)sp * NPTS + q0w + sub * 16 + qi) * 64 + ft * 16 + quad * 4) = o;
        }
        if (lane < 16) {
            Ms[sp * NPTS + q0w + sub * 16 + lane] = m_i[sub];
            Ls[sp * NPTS + q0w + sub * 16 + lane] = l_i[sub];
        }
    }
}

// ---------------- merge partials + @Wt (MFMA) + fused BN-stats ----------------
__global__ __launch_bounds__(256) void merge_gemm(const _Float16* __restrict__ Op,
                                                  const float* __restrict__ Ms, const float* __restrict__ Ls,
                                                  const _Float16* __restrict__ Wtf,
                                                  float* __restrict__ xr, float* __restrict__ stats_out) {
    __shared__ float w8[64][8];
    __shared__ float Linv[64];
    __shared__ __align__(16) _Float16 Ah[64 * 72], Al[64 * 72];
    __shared__ float s_sum[64], s_ss[64];
    int t = threadIdx.x;
    int row0 = blockIdx.x * 64;
    if (t < 64) {
        int q = row0 + t;
        float m[8], M = -1e30f;
#pragma unroll
        for (int s = 0; s < 8; s++) {
            m[s] = Ms[s * NPTS + q];
            M = fmaxf(M, m[s]);
        }
        float L = 0.f;
#pragma unroll
        for (int s = 0; s < 8; s++) {
            float w = __expf(m[s] - M);
            w8[t][s] = w;
            L += Ls[s * NPTS + q] * w;
        }
        Linv[t] = 1.f / L;
        s_sum[t] = 0.f;
        s_ss[t] = 0.f;
    }
    __syncthreads();
    for (int k = 0; k < 4; k++) {
        int i = t + k * 256;
        int qr = i >> 4, f4 = (i & 15) * 4;
        int q = row0 + qr;
        float acc[4] = {0.f, 0.f, 0.f, 0.f};
#pragma unroll
        for (int s = 0; s < 8; s++) {
            float w = w8[qr][s];
            half4 o = *(const half4*)(Op + ((size_t)s * NPTS + q) * 64 + f4);
#pragma unroll
            for (int c = 0; c < 4; c++) acc[c] += (float)o[c] * w;
        }
        float inv = Linv[qr];
#pragma unroll
        for (int c = 0; c < 4; c++) {
            float val = acc[c] * inv;
            _Float16 h = (_Float16)val;
            Ah[qr * 72 + f4 + c] = h;
            Al[qr * 72 + f4 + c] = (_Float16)(val - (float)h);
        }
    }
    __syncthreads();
    int lane = t & 63, wv = t >> 6;
    int quad = lane >> 4, qi = lane & 15;
    int rloc = wv * 16 + qi;
    half8 ah[2], al[2];
#pragma unroll
    for (int s = 0; s < 2; s++) {
        ah[s] = *(const half8*)(Ah + rloc * 72 + s * 32 + quad * 8);
        al[s] = *(const half8*)(Al + rloc * 72 + s * 32 + quad * 8);
    }
    floatx4 C[4];
#pragma unroll
    for (int ct = 0; ct < 4; ct++) C[ct] = floatx4{0.f, 0.f, 0.f, 0.f};
#pragma unroll
    for (int ct = 0; ct < 4; ct++)
#pragma unroll
        for (int s = 0; s < 2; s++) {
            half8 b = *(const half8*)(Wtf + (s * 4 + ct) * 512 + lane * 8);
            C[ct] = __builtin_amdgcn_mfma_f32_16x16x32_f16(ah[s], b, C[ct], 0, 0, 0);
            C[ct] = __builtin_amdgcn_mfma_f32_16x16x32_f16(al[s], b, C[ct], 0, 0, 0);
        }
    int orow = row0 + wv * 16 + quad * 4;
#pragma unroll
    for (int ct = 0; ct < 4; ct++) {
        int f = ct * 16 + qi;
        float ps = 0.f, pss = 0.f;
#pragma unroll
        for (int r = 0; r < 4; r++) {
            float v = C[ct][r];
            xr[(size_t)(orow + r) * 64 + f] = v;
            ps += v;
            pss += v * v;
        }
        atomicAdd(&s_sum[f], ps);
        atomicAdd(&s_ss[f], pss);
    }
    __syncthreads();
    if (t < 64) {
        atomicAdd(&stats_out[t], s_sum[t]);
        atomicAdd(&stats_out[64 + t], s_ss[t]);
    }
}

// ---------------- Stage-2 ragged flash attention (R6 version, unchanged) ----------------
__global__ __launch_bounds__(256) void flash2_mfma(const _Float16* __restrict__ Qh,
                                                   const _Float16* __restrict__ Ql,
                                                   const _Float16* __restrict__ Kh,
                                                   const _Float16* __restrict__ Vt2,
                                                   const int* __restrict__ pad_idx,
                                                   const int* __restrict__ counts,
                                                   _Float16* __restrict__ O) {
    int b = blockIdx.y;
    int c = counts[b];
    int qb = blockIdx.x;
    if (qb * 64 >= c) return;
    __shared__ __align__(16) _Float16 KsF[8 * 512];
    __shared__ __align__(16) _Float16 VsF[8 * 512];
    __shared__ __align__(16) _Float16 PTF[4][2 * 512];
    int t = threadIdx.x;
    int lane = t & 63, wv = t >> 6;
    int quad = lane >> 4, qi = lane & 15;
    const int* prow = pad_idx + b * LQPAD;
    int p_q = qb * 64 + wv * 16 + qi;
    int flat_q = (p_q < LQPAD) ? prow[p_q] : -1;

    half8 qh[2], ql[2];
#pragma unroll
    for (int s = 0; s < 2; s++) {
        if (flat_q >= 0) {
            qh[s] = *(const half8*)(Qh + (size_t)flat_q * 64 + s * 32 + quad * 8);
            ql[s] = *(const half8*)(Ql + (size_t)flat_q * 64 + s * 32 + quad * 8);
        } else {
            qh[s] = half8{0, 0, 0, 0, 0, 0, 0, 0};
            ql[s] = half8{0, 0, 0, 0, 0, 0, 0, 0};
        }
    }
    floatx4 Oacc[4];
#pragma unroll
    for (int ft = 0; ft < 4; ft++) Oacc[ft] = floatx4{0.f, 0.f, 0.f, 0.f};
    float m_i = -1e30f, l_i = 0.f;
    const _Float16* VtB = Vt2 + (size_t)b * 64 * LPAD2;

    int nt = (c + 63) >> 6;
    for (int it = 0; it < nt; it++) {
        int k0 = it * 64;
        __syncthreads();
#pragma unroll
        for (int u = 0; u < 4; u++) {
            int frag = wv + 4 * u;
            if (frag < 8) {
                int kt = frag >> 1, s = frag & 1;
                int kp = k0 + kt * 16 + qi;
                int flat = (kp < c) ? prow[kp] : -1;
                int d0 = s * 32 + quad * 8;
                half8 kvv = half8{0, 0, 0, 0, 0, 0, 0, 0};
                if (flat >= 0) kvv = *(const half8*)(Kh + (size_t)flat * 64 + d0);
                *(half8*)(KsF + frag * 512 + lane * 8) = kvv;
            } else {
                int fr = frag - 8;
                int ft = fr >> 1, s = fr & 1;
                int f = ft * 16 + qi;
                int key = k0 + s * 32 + quad * 8;
                *(half8*)(VsF + fr * 512 + lane * 8) = *(const half8*)(VtB + f * LPAD2 + key);
            }
        }
        __syncthreads();
        floatx4 st[4];
#pragma unroll
        for (int kt = 0; kt < 4; kt++) {
            floatx4 acc = floatx4{0.f, 0.f, 0.f, 0.f};
#pragma unroll
            for (int s = 0; s < 2; s++) {
                half8 a = *(const half8*)(KsF + (kt * 2 + s) * 512 + lane * 8);
                acc = __builtin_amdgcn_mfma_f32_16x16x32_f16(a, qh[s], acc, 0, 0, 0);
                acc = __builtin_amdgcn_mfma_f32_16x16x32_f16(a, ql[s], acc, 0, 0, 0);
            }
            st[kt] = acc;
        }
        float mloc = -1e30f;
#pragma unroll
        for (int kt = 0; kt < 4; kt++)
#pragma unroll
            for (int r = 0; r < 4; r++) mloc = fmaxf(mloc, st[kt][r]);
        mloc = fmaxf(mloc, __shfl_xor(mloc, 16));
        mloc = fmaxf(mloc, __shfl_xor(mloc, 32));
        float m_new = fmaxf(m_i, mloc);
        float alpha = __expf(m_i - m_new);
        float ps = 0.f;
#pragma unroll
        for (int kt = 0; kt < 4; kt++) {
            half4 pk;
#pragma unroll
            for (int r = 0; r < 4; r++) {
                int kpos = k0 + kt * 16 + quad * 4 + r;
                float p = (kpos < c) ? __expf(st[kt][r] - m_new) : 0.f;
                ps += p;
                pk[r] = (_Float16)p;
            }
            int s = kt >> 1;
            int qd2 = (kt & 1) * 2 + (quad >> 1);
            *(half4*)(&PTF[wv][(s * 64 + qd2 * 16 + qi) * 8 + (quad & 1) * 4]) = pk;
        }
        ps += __shfl_xor(ps, 16);
        ps += __shfl_xor(ps, 32);
        l_i = l_i * alpha + ps;
        m_i = m_new;
#pragma unroll
        for (int ft = 0; ft < 4; ft++) Oacc[ft] *= alpha;
        half8 pb[2];
#pragma unroll
        for (int s = 0; s < 2; s++) pb[s] = *(const half8*)(&PTF[wv][(s * 64 + lane) * 8]);
#pragma unroll
        for (int ft = 0; ft < 4; ft++)
#pragma unroll
            for (int s = 0; s < 2; s++) {
                half8 a = *(const half8*)(VsF + (ft * 2 + s) * 512 + lane * 8);
                Oacc[ft] = __builtin_amdgcn_mfma_f32_16x16x32_f16(a, pb[s], Oacc[ft], 0, 0, 0);
            }
    }
    if (flat_q >= 0) {
        float inv = 1.f / l_i;
#pragma unroll
        for (int ft = 0; ft < 4; ft++) {
            half4 o;
#pragma unroll
            for (int r = 0; r < 4; r++) o[r] = (_Float16)(Oacc[ft][r] * inv);
            *(half4*)(O + (size_t)flat_q * 64 + ft * 16 + quad * 4) = o;
        }
    }
}

extern "C" void kernel_launch(void* const* d_in, const int* in_sizes, int n_in,
                              void* d_out, int out_size, void* d_ws, size_t ws_size,
                              hipStream_t stream) {
    const float* x_dec = (const float*)d_in[0];
    const float* x_enc = (const float*)d_in[1];
    const float* Wp1 = (const float*)d_in[2];
    const float* Wq = (const float*)d_in[3];
    const float* Wk = (const float*)d_in[4];
    const float* Wv = (const float*)d_in[5];
    const float* Wt_ = (const float*)d_in[6];
    const float* Wq1 = (const float*)d_in[7];
    const float* Wk1 = (const float*)d_in[8];
    const float* Wv1 = (const float*)d_in[9];
    const float* Wdown = (const float*)d_in[10];
    const float* W3t = (const float*)d_in[11];
    const float* W3a = (const float*)d_in[12];
    const float* W3b = (const float*)d_in[13];
    const float* bn_g = (const float*)d_in[14];
    const float* bn_b = (const float*)d_in[15];
    const int* nbr = (const int*)d_in[16];
    const int* kv_nbr = (const int*)d_in[17];
    const int* pad_idx = (const int*)d_in[18];
    const int* unpad_idx = (const int*)d_in[19];
    float* out = (float*)d_out;
    float* ws = (float*)d_ws;

    const int N = NPTS;
    const size_t BUF = (size_t)N * 64;
    // slot map (3 MB each):
    float* xd = ws;                          // 0
    float* slot1 = ws + BUF;                 // Oph[0] -> Vt2
    float* slot2 = ws + 2 * BUF;             // Oph[1] -> Qh1/Ql1
    float* slot3 = ws + 3 * BUF;             // Oph[2] -> z2
    float* slot4 = ws + 4 * BUF;             // Oph[3] -> z2h
    float* slot5 = ws + 5 * BUF;             // Qh/Ql -> kv
    float* slot6 = ws + 6 * BUF;             // Kh/Vt -> Kh1 -> xr2h
    float* slot7 = ws + 7 * BUF;             // xr -> xrh
    float* slot8 = ws + 8 * BUF;             // xr2 -> o2
    float* arena = ws + 9 * BUF;             // stats | counts | Ms/Ls | Wf | Wpq

    float* stats = arena;                    // 768 floats (6 slots x 128)
    int* counts = (int*)(arena + 768);       // 8 ints (within first 1024)
    float* Ms = arena + 1024;                // 8*NPTS
    float* Ls = Ms + 8 * NPTS;               // 8*NPTS
    _Float16* WfA = (_Float16*)(Ls + 8 * NPTS);  // 97*4096 fp16
    float* Wpq = (float*)(WfA + (size_t)97 * 4096);  // 4096 fp32

    _Float16* Oph = (_Float16*)slot1;        // 8*NPTS*64 fp16 = slots 1..4
    _Float16* Qh = (_Float16*)slot5;
    _Float16* Ql = Qh + BUF;
    _Float16* Kh = (_Float16*)slot6;
    _Float16* Vt = Kh + BUF;
    float* kv = slot5;
    _Float16* Qh1 = (_Float16*)slot2;
    _Float16* Ql1 = Qh1 + BUF;
    _Float16* Kh1 = (_Float16*)slot6;
    _Float16* Vt2 = (_Float16*)slot1;
    _Float16* z2h = (_Float16*)slot4;
    float* xr = slot7;
    _Float16* xrh = (_Float16*)slot7;
    float* xr2 = slot8;
    float* o2 = slot8;
    _Float16* xr2h = (_Float16*)slot6;
    float* z2 = slot3;

    const _Float16* Wp1f = WfA;
    const _Float16* Wpqf = WfA + 1 * 4096;
    const _Float16* Wtf = WfA + 4 * 4096;
    const _Float16* Wq1f = WfA + 5 * 4096;
    const _Float16* Wk1f = WfA + 6 * 4096;
    const _Float16* Wv1f = WfA + 7 * 4096;
    const _Float16* Wdf = WfA + 8 * 4096;
    const _Float16* W3tf = WfA + (size_t)16 * 4096;
    const _Float16* W3af = WfA + (size_t)43 * 4096;
    const _Float16* W3bf = WfA + (size_t)70 * 4096;
    (void)Wp1f;

    hipMemsetAsync(stats, 0, 1024 * sizeof(float), stream);

    dim3 B(256);
    int gG = N / 64;  // 192

    wprod<<<1, B, 0, stream>>>(Wp1, Wq, Wpq);
    pack_all<<<97, B, 0, stream>>>(Wp1, Wpq, Wk, Wv, Wt_, Wq1, Wk1, Wv1, Wdown, W3t, W3a, W3b, WfA);
    count_valid<<<8, B, 0, stream>>>(pad_idx, counts);

    gemm_head<<<dim3(gG, 4), B, 0, stream>>>(x_dec, x_enc, WfA, xd, Qh, Ql, Kh, Vt);
    flash1_mfma<<<dim3(N / 128, 8), B, 0, stream>>>(Qh, Ql, Kh, Vt, Oph, Ms, Ls);
    merge_gemm<<<gG, B, 0, stream>>>(Oph, Ms, Ls, Wtf, xr, stats + 0);
    bn_apply<<<256, B, 0, stream>>>(xr, nullptr, xd, xd, nullptr, stats + 0, bn_g + 0, bn_b + 0,
                                    nullptr, N, 0);

    gemm_split<<<gG, B, 0, stream>>>(xd, Wq1f, Qh1, Ql1);
    gconv_mfma<<<gG, B, 0, stream>>>(Qh1, kv_nbr, Wdf, kv, 8, nullptr, stats + 128);
    gemm_kv1<<<dim3(gG, 2), B, 0, stream>>>(kv, Wk1f, Wv1f, stats + 128, bn_g + 64, bn_b + 64,
                                            unpad_idx, Kh1, Vt2);
    flash2_mfma<<<dim3(LPAD2 / 64, 8), B, 0, stream>>>(Qh1, Ql1, Kh1, Vt2, pad_idx, counts, z2h);
    gconv_mfma<<<gG, B, 0, stream>>>(z2h, nbr, W3tf, xr2, 27, nullptr, stats + 256);
    bn_apply<<<256, B, 0, stream>>>(xr2, nullptr, xd, xd, nullptr, stats + 256, bn_g + 128, bn_b + 128,
                                    stats + 384, N, 0);

    bn_apply<<<256, B, 0, stream>>>(xd, nullptr, nullptr, nullptr, xrh, stats + 384, bn_g + 192,
                                    bn_b + 192, nullptr, N, 1);
    gconv_mfma<<<gG, B, 0, stream>>>(xrh, nbr, W3af, o2, 27, nullptr, stats + 512);
    bn_apply<<<256, B, 0, stream>>>(o2, nullptr, nullptr, nullptr, xr2h, stats + 512, bn_g + 256,
                                    bn_b + 256, nullptr, N, 1);
    gconv_mfma<<<gG, B, 0, stream>>>(xr2h, nbr, W3bf, z2, 27, xd, stats + 640);
    bn_apply<<<256, B, 0, stream>>>(xd, z2, nullptr, out, nullptr, stats + 640, bn_g + 320, bn_b + 320,
                                    nullptr, N, 1);
}

// Round 8
// 415.185 us; speedup vs baseline: 1.7292x; 1.0444x over previous
//
#include <hip/hip_runtime.h>

#define NPTS 12288
#define LQPAD 1800
#define LPAD2 1856
#define EPSBN 1e-4f

typedef _Float16 half8 __attribute__((ext_vector_type(8)));
typedef _Float16 half4 __attribute__((ext_vector_type(4)));
typedef float floatx4 __attribute__((ext_vector_type(4)));

// ---------------- Wpq = Wp1 @ Wq (fp32, 16 blocks x 4 rows) ----------------
__global__ __launch_bounds__(256) void wprod16(const float* __restrict__ Wp1, const float* __restrict__ Wq,
                                               float* __restrict__ Wpq) {
    __shared__ float Bs[4096];
    __shared__ float As[4][64];
    int t = threadIdx.x;
    for (int i = t; i < 4096; i += 256) Bs[i] = Wq[i];
    int r0 = blockIdx.x * 4;
    {
        int i = t >> 6, k = t & 63;
        As[i][k] = Wp1[(r0 + i) * 64 + k];
    }
    __syncthreads();
    int i = t >> 6, j = t & 63;
    float s = 0.f;
#pragma unroll
    for (int k = 0; k < 64; k++) s += As[i][k] * Bs[k * 64 + j];
    Wpq[(r0 + i) * 64 + j] = s;
}

// ---------------- pack ALL weights into B-fragment-major fp16 arena ----------------
__global__ __launch_bounds__(256) void pack_all(const float* Wp1, const float* Wpq, const float* Wk,
                                                const float* Wv, const float* Wt_, const float* Wq1,
                                                const float* Wk1, const float* Wv1, const float* Wdown,
                                                const float* W3t, const float* W3a, const float* W3b,
                                                _Float16* __restrict__ Wf) {
    int g = blockIdx.x;
    const float* src;
    if (g == 0) src = Wp1;
    else if (g == 1) src = Wpq;
    else if (g == 2) src = Wk;
    else if (g == 3) src = Wv;
    else if (g == 4) src = Wt_;
    else if (g == 5) src = Wq1;
    else if (g == 6) src = Wk1;
    else if (g == 7) src = Wv1;
    else if (g < 16) src = Wdown + (size_t)(g - 8) * 4096;
    else if (g < 43) src = W3t + (size_t)(g - 16) * 4096;
    else if (g < 70) src = W3a + (size_t)(g - 43) * 4096;
    else src = W3b + (size_t)(g - 70) * 4096;
    int t = threadIdx.x;
    int lane = t & 63, fg = t >> 6;
    int quad = lane >> 4, qi = lane & 15;
#pragma unroll
    for (int u = 0; u < 2; u++) {
        int frag = fg * 2 + u;
        int s = frag >> 2, ct = frag & 3;
        half8 v;
#pragma unroll
        for (int j = 0; j < 8; j++) v[j] = (_Float16)src[(s * 32 + quad * 8 + j) * 64 + ct * 16 + qi];
        *(half8*)(Wf + (size_t)g * 4096 + frag * 512 + lane * 8) = v;
    }
}

// A fp32 row -> hi/lo half8 fragments
__device__ inline void load_split8(const float* p, half8& hi, half8& lo) {
    float4 a = *(const float4*)p;
    float4 b = *(const float4*)(p + 4);
    float v[8] = {a.x, a.y, a.z, a.w, b.x, b.y, b.z, b.w};
#pragma unroll
    for (int j = 0; j < 8; j++) {
        _Float16 h = (_Float16)v[j];
        hi[j] = h;
        lo[j] = (_Float16)(v[j] - (float)h);
    }
}

// ---------------- gemm_head: 4 GEMMs in one launch (stage-1 inputs) ----------------
__global__ __launch_bounds__(256) void gemm_head(const float* __restrict__ xdec, const float* __restrict__ xenc,
                                                 const _Float16* __restrict__ Wf, float* __restrict__ xd,
                                                 _Float16* __restrict__ Qh, _Float16* __restrict__ Ql,
                                                 _Float16* __restrict__ Kh, _Float16* __restrict__ Vt) {
    int z = blockIdx.y;
    const float* A = (z < 2) ? xdec : xenc;
    const _Float16* Bf = Wf + (size_t)z * 4096;
    int t = threadIdx.x;
    int lane = t & 63, wv = t >> 6;
    int quad = lane >> 4, qi = lane & 15;
    int row0w = blockIdx.x * 64 + wv * 16;
    half8 ah[2], al[2];
#pragma unroll
    for (int s = 0; s < 2; s++) load_split8(A + (size_t)(row0w + qi) * 64 + s * 32 + quad * 8, ah[s], al[s]);
    floatx4 C[4];
#pragma unroll
    for (int ct = 0; ct < 4; ct++) C[ct] = floatx4{0.f, 0.f, 0.f, 0.f};
#pragma unroll
    for (int ct = 0; ct < 4; ct++)
#pragma unroll
        for (int s = 0; s < 2; s++) {
            half8 b = *(const half8*)(Bf + (s * 4 + ct) * 512 + lane * 8);
            C[ct] = __builtin_amdgcn_mfma_f32_16x16x32_f16(ah[s], b, C[ct], 0, 0, 0);
            C[ct] = __builtin_amdgcn_mfma_f32_16x16x32_f16(al[s], b, C[ct], 0, 0, 0);
        }
    int orow = row0w + quad * 4;
    if (z == 0) {
#pragma unroll
        for (int ct = 0; ct < 4; ct++)
#pragma unroll
            for (int r = 0; r < 4; r++) xd[(size_t)(orow + r) * 64 + ct * 16 + qi] = C[ct][r];
    } else if (z == 1) {
#pragma unroll
        for (int ct = 0; ct < 4; ct++)
#pragma unroll
            for (int r = 0; r < 4; r++) {
                float v = C[ct][r];
                _Float16 h = (_Float16)v;
                Qh[(size_t)(orow + r) * 64 + ct * 16 + qi] = h;
                Ql[(size_t)(orow + r) * 64 + ct * 16 + qi] = (_Float16)(v - (float)h);
            }
    } else if (z == 2) {
#pragma unroll
        for (int ct = 0; ct < 4; ct++)
#pragma unroll
            for (int r = 0; r < 4; r++) Kh[(size_t)(orow + r) * 64 + ct * 16 + qi] = (_Float16)C[ct][r];
    } else {
#pragma unroll
        for (int ct = 0; ct < 4; ct++) {
            half4 o;
#pragma unroll
            for (int r = 0; r < 4; r++) o[r] = (_Float16)C[ct][r];
            *(half4*)(Vt + (size_t)(ct * 16 + qi) * NPTS + orow) = o;
        }
    }
}

// ---------------- gemm_q1: fused [xd += BN(xr)] prologue + q1 = xd@Wq1 split output -------
__global__ __launch_bounds__(256) void gemm_q1(const float* __restrict__ xr, float* __restrict__ xd,
                                               const _Float16* __restrict__ Bf,
                                               const float* __restrict__ stats,
                                               const float* __restrict__ gamma,
                                               const float* __restrict__ beta,
                                               _Float16* __restrict__ Oh, _Float16* __restrict__ Ol) {
    int t = threadIdx.x;
    int lane = t & 63, wv = t >> 6;
    int quad = lane >> 4, qi = lane & 15;
    int row0w = blockIdx.x * 64 + wv * 16;
    const float inv_n = 1.f / (float)NPTS;
    half8 ah[2], al[2];
#pragma unroll
    for (int s = 0; s < 2; s++) {
        size_t base = (size_t)(row0w + qi) * 64 + s * 32 + quad * 8;
        float4 xa = *(const float4*)(xr + base);
        float4 xb = *(const float4*)(xr + base + 4);
        float4 da = *(const float4*)(xd + base);
        float4 db = *(const float4*)(xd + base + 4);
        float vx[8] = {xa.x, xa.y, xa.z, xa.w, xb.x, xb.y, xb.z, xb.w};
        float vd[8] = {da.x, da.y, da.z, da.w, db.x, db.y, db.z, db.w};
        float vo[8];
#pragma unroll
        for (int j = 0; j < 8; j++) {
            int f = s * 32 + quad * 8 + j;
            float mean = stats[f] * inv_n;
            float var = stats[64 + f] * inv_n - mean * mean;
            float val = vd[j] + (vx[j] - mean) * rsqrtf(var + EPSBN) * gamma[f] + beta[f];
            vo[j] = val;
            _Float16 h = (_Float16)val;
            ah[s][j] = h;
            al[s][j] = (_Float16)(val - (float)h);
        }
        *(float4*)(xd + base) = float4{vo[0], vo[1], vo[2], vo[3]};
        *(float4*)(xd + base + 4) = float4{vo[4], vo[5], vo[6], vo[7]};
    }
    floatx4 C[4];
#pragma unroll
    for (int ct = 0; ct < 4; ct++) C[ct] = floatx4{0.f, 0.f, 0.f, 0.f};
#pragma unroll
    for (int ct = 0; ct < 4; ct++)
#pragma unroll
        for (int s = 0; s < 2; s++) {
            half8 b = *(const half8*)(Bf + (s * 4 + ct) * 512 + lane * 8);
            C[ct] = __builtin_amdgcn_mfma_f32_16x16x32_f16(ah[s], b, C[ct], 0, 0, 0);
            C[ct] = __builtin_amdgcn_mfma_f32_16x16x32_f16(al[s], b, C[ct], 0, 0, 0);
        }
    int orow = row0w + quad * 4;
#pragma unroll
    for (int ct = 0; ct < 4; ct++)
#pragma unroll
        for (int r = 0; r < 4; r++) {
            float v = C[ct][r];
            _Float16 h = (_Float16)v;
            Oh[(size_t)(orow + r) * 64 + ct * 16 + qi] = h;
            Ol[(size_t)(orow + r) * 64 + ct * 16 + qi] = (_Float16)(v - (float)h);
        }
}

// ---------------- gemm_kv1: BN(kv) fused prologue; y=0 -> Kh1, y=1 -> Vt2 scatter ---------
__global__ __launch_bounds__(256) void gemm_kv1(const float* __restrict__ kv, const _Float16* __restrict__ Wfk,
                                                const _Float16* __restrict__ Wfv,
                                                const float* __restrict__ stats, const float* __restrict__ gamma,
                                                const float* __restrict__ beta, const int* __restrict__ unpad,
                                                _Float16* __restrict__ Kh1, _Float16* __restrict__ Vt2) {
    int y = blockIdx.y;
    int t = threadIdx.x;
    int lane = t & 63, wv = t >> 6;
    int quad = lane >> 4, qi = lane & 15;
    int row0w = blockIdx.x * 64 + wv * 16;
    const float inv_n = 1.f / (float)NPTS;
    half8 ah[2], al[2];
#pragma unroll
    for (int s = 0; s < 2; s++) {
        const float* p = kv + (size_t)(row0w + qi) * 64 + s * 32 + quad * 8;
        float4 a = *(const float4*)p;
        float4 b2 = *(const float4*)(p + 4);
        float v[8] = {a.x, a.y, a.z, a.w, b2.x, b2.y, b2.z, b2.w};
#pragma unroll
        for (int j = 0; j < 8; j++) {
            int f = s * 32 + quad * 8 + j;
            float mean = stats[f] * inv_n;
            float var = stats[64 + f] * inv_n - mean * mean;
            float val = (v[j] - mean) * rsqrtf(var + EPSBN) * gamma[f] + beta[f];
            _Float16 h = (_Float16)val;
            ah[s][j] = h;
            al[s][j] = (_Float16)(val - (float)h);
        }
    }
    const _Float16* Bf = y ? Wfv : Wfk;
    floatx4 C[4];
#pragma unroll
    for (int ct = 0; ct < 4; ct++) C[ct] = floatx4{0.f, 0.f, 0.f, 0.f};
#pragma unroll
    for (int ct = 0; ct < 4; ct++)
#pragma unroll
        for (int s = 0; s < 2; s++) {
            half8 b = *(const half8*)(Bf + (s * 4 + ct) * 512 + lane * 8);
            C[ct] = __builtin_amdgcn_mfma_f32_16x16x32_f16(ah[s], b, C[ct], 0, 0, 0);
            C[ct] = __builtin_amdgcn_mfma_f32_16x16x32_f16(al[s], b, C[ct], 0, 0, 0);
        }
    int orow = row0w + quad * 4;
    if (y == 0) {
#pragma unroll
        for (int ct = 0; ct < 4; ct++)
#pragma unroll
            for (int r = 0; r < 4; r++) Kh1[(size_t)(orow + r) * 64 + ct * 16 + qi] = (_Float16)C[ct][r];
    } else {
        int u0 = unpad[orow], u3 = unpad[orow + 3];
        int b0 = u0 / 1800, b3 = u3 / 1800;
        if (u3 == u0 + 3 && b0 == b3) {
            int p0 = u0 - b0 * 1800;
#pragma unroll
            for (int ct = 0; ct < 4; ct++) {
                half4 o;
#pragma unroll
                for (int r = 0; r < 4; r++) o[r] = (_Float16)C[ct][r];
                *(half4*)(Vt2 + ((size_t)b0 * 64 + ct * 16 + qi) * LPAD2 + p0) = o;
            }
        } else {
#pragma unroll
            for (int r = 0; r < 4; r++) {
                int u = unpad[orow + r];
                int b = u / 1800, p = u - b * 1800;
#pragma unroll
                for (int ct = 0; ct < 4; ct++)
                    Vt2[((size_t)b * 64 + ct * 16 + qi) * LPAD2 + p] = (_Float16)C[ct][r];
            }
        }
    }
}

// ---------------- gather conv, MFMA, f-split x2 (grid = 2*N/64), fused BN-stats ----------
__global__ __launch_bounds__(256) void gconv_mfma(const _Float16* __restrict__ Xh,
                                                  const int* __restrict__ idx,
                                                  const _Float16* __restrict__ Wf,
                                                  float* __restrict__ OUT, int nk,
                                                  const float* Xadd, float* stats_out) {
    __shared__ float s_sum[64], s_ss[64];
    int t = threadIdx.x;
    int lane = t & 63, wv = t >> 6;
    int quad = lane >> 4, qi = lane & 15;
    int bx = blockIdx.x;
    int row0 = (bx >> 1) * 64 + wv * 16;
    int cb = (bx & 1) * 2;
    if (stats_out) {
        if (t < 64) {
            s_sum[t] = 0.f;
            s_ss[t] = 0.f;
        }
        __syncthreads();
    }
    floatx4 Oacc[2];
#pragma unroll
    for (int u = 0; u < 2; u++) Oacc[u] = floatx4{0.f, 0.f, 0.f, 0.f};
    const int* ip = idx + (size_t)(row0 + qi) * nk;
    for (int k = 0; k < nk; k++) {
        int j = ip[k];
        half8 a0 = half8{0, 0, 0, 0, 0, 0, 0, 0};
        half8 a1 = half8{0, 0, 0, 0, 0, 0, 0, 0};
        if (j >= 0) {
            a0 = *(const half8*)(Xh + (size_t)j * 64 + quad * 8);
            a1 = *(const half8*)(Xh + (size_t)j * 64 + 32 + quad * 8);
        }
        const _Float16* wk = Wf + (size_t)k * 4096;
#pragma unroll
        for (int u = 0; u < 2; u++) {
            int ct = cb + u;
            half8 b0 = *(const half8*)(wk + ct * 512 + lane * 8);
            half8 b1 = *(const half8*)(wk + (4 + ct) * 512 + lane * 8);
            Oacc[u] = __builtin_amdgcn_mfma_f32_16x16x32_f16(a0, b0, Oacc[u], 0, 0, 0);
            Oacc[u] = __builtin_amdgcn_mfma_f32_16x16x32_f16(a1, b1, Oacc[u], 0, 0, 0);
        }
    }
    int orow = row0 + quad * 4;
#pragma unroll
    for (int u = 0; u < 2; u++) {
        int ct = cb + u;
#pragma unroll
        for (int r = 0; r < 4; r++) OUT[(size_t)(orow + r) * 64 + ct * 16 + qi] = Oacc[u][r];
    }
    if (stats_out) {
#pragma unroll
        for (int u = 0; u < 2; u++) {
            int f = (cb + u) * 16 + qi;
            float ps = 0.f, pss = 0.f;
#pragma unroll
            for (int r = 0; r < 4; r++) {
                float v = Oacc[u][r];
                if (Xadd) v += Xadd[(size_t)(orow + r) * 64 + f];
                ps += v;
                pss += v * v;
            }
            atomicAdd(&s_sum[f], ps);
            atomicAdd(&s_ss[f], pss);
        }
        __syncthreads();
        if (t < 64) {
            atomicAdd(&stats_out[t], s_sum[t]);
            atomicAdd(&stats_out[64 + t], s_ss[t]);
        }
    }
}

// ---------------- bn_apply ----------------
__global__ __launch_bounds__(256) void bn_apply(const float* __restrict__ X, const float* X2,
                                                const float* R, float* OUT, _Float16* OUT16,
                                                const float* __restrict__ stats,
                                                const float* __restrict__ gamma,
                                                const float* __restrict__ beta,
                                                float* stats_out, int n, int do_relu) {
    __shared__ float sh[2][4][64];
    int t = threadIdx.x;
    int f = t & 63, g = t >> 6;
    float inv_n = 1.f / (float)n;
    float mean = stats[f] * inv_n;
    float var = stats[64 + f] * inv_n - mean * mean;
    float rstd = rsqrtf(var + EPSBN);
    float ga = gamma[f], be = beta[f];
    float s = 0.f, ss = 0.f;
    for (int r = blockIdx.x * 4 + g; r < n; r += gridDim.x * 4) {
        size_t i = (size_t)r * 64 + f;
        float v = X[i];
        if (X2) v += X2[i];
        v = (v - mean) * rstd * ga + be;
        if (R) v += R[i];
        if (do_relu) v = fmaxf(v, 0.f);
        if (OUT) OUT[i] = v;
        if (OUT16) OUT16[i] = (_Float16)v;
        s += v;
        ss += v * v;
    }
    if (stats_out) {
        sh[0][g][f] = s;
        sh[1][g][f] = ss;
        __syncthreads();
        if (g == 0) {
            s = sh[0][0][f] + sh[0][1][f] + sh[0][2][f] + sh[0][3][f];
            ss = sh[1][0][f] + sh[1][1][f] + sh[1][2][f] + sh[1][3][f];
            atomicAdd(&stats_out[f], s);
            atomicAdd(&stats_out[64 + f], ss);
        }
    }
}

// ---------------- per-batch valid counts ----------------
__global__ __launch_bounds__(256) void count_valid(const int* __restrict__ pad_idx, int* __restrict__ counts) {
    int b = blockIdx.x;
    int t = threadIdx.x;
    int s = 0;
    for (int i = t; i < LQPAD; i += 256) s += (pad_idx[b * LQPAD + i] >= 0) ? 1 : 0;
    for (int off = 32; off > 0; off >>= 1) s += __shfl_xor(s, off);
    if ((t & 63) == 0) atomicAdd(&counts[b], s);
}

// ---------------- Stage-1 flash attention: K-tile 128, two 64-key softmax chunks ----------
__global__ __launch_bounds__(256, 3) void flash1_mfma(const _Float16* __restrict__ Qh,
                                                      const _Float16* __restrict__ Ql,
                                                      const _Float16* __restrict__ Kh,
                                                      const _Float16* __restrict__ Vt,
                                                      _Float16* __restrict__ Op,
                                                      float* __restrict__ Ms,
                                                      float* __restrict__ Ls) {
    __shared__ __align__(16) _Float16 KsF[16 * 512];
    __shared__ __align__(16) _Float16 VsF[16 * 512];
    __shared__ __align__(16) _Float16 PTF[4][2 * 1024];
    int t = threadIdx.x;
    int lane = t & 63, wv = t >> 6;
    int quad = lane >> 4, qi = lane & 15;
    int qb = blockIdx.x, sp = blockIdx.y;
    int q0w = qb * 128 + wv * 32;

    half8 qh[2][2], ql[2][2];
#pragma unroll
    for (int sub = 0; sub < 2; sub++)
#pragma unroll
        for (int s = 0; s < 2; s++) {
            int qrow = q0w + sub * 16 + qi;
            qh[sub][s] = *(const half8*)(Qh + (size_t)qrow * 64 + s * 32 + quad * 8);
            ql[sub][s] = *(const half8*)(Ql + (size_t)qrow * 64 + s * 32 + quad * 8);
        }
    floatx4 Oacc[2][4];
#pragma unroll
    for (int sub = 0; sub < 2; sub++)
#pragma unroll
        for (int ft = 0; ft < 4; ft++) Oacc[sub][ft] = floatx4{0.f, 0.f, 0.f, 0.f};
    float m_i[2] = {-1e30f, -1e30f}, l_i[2] = {0.f, 0.f};

    for (int it = 0; it < 12; it++) {
        int k0 = sp * 1536 + it * 128;
        __syncthreads();
#pragma unroll
        for (int u = 0; u < 8; u++) {
            int frag = wv + 4 * u;
            if (frag < 16) {
                int kt = frag >> 1, s = frag & 1;
                int key = k0 + kt * 16 + qi;
                *(half8*)(KsF + frag * 512 + lane * 8) =
                    *(const half8*)(Kh + (size_t)key * 64 + s * 32 + quad * 8);
            } else {
                int fr = frag - 16;
                int ft = fr >> 2, s = fr & 3;
                int f = ft * 16 + qi;
                *(half8*)(VsF + fr * 512 + lane * 8) =
                    *(const half8*)(Vt + (size_t)f * NPTS + k0 + s * 32 + quad * 8);
            }
        }
        __syncthreads();
#pragma unroll
        for (int ch = 0; ch < 2; ch++) {
            half8 ka[4][2];
#pragma unroll
            for (int kt = 0; kt < 4; kt++)
#pragma unroll
                for (int s = 0; s < 2; s++)
                    ka[kt][s] = *(const half8*)(KsF + ((ch * 4 + kt) * 2 + s) * 512 + lane * 8);
            floatx4 st[2][4];
#pragma unroll
            for (int sub = 0; sub < 2; sub++)
#pragma unroll
                for (int kt = 0; kt < 4; kt++) {
                    floatx4 acc = floatx4{0.f, 0.f, 0.f, 0.f};
#pragma unroll
                    for (int s = 0; s < 2; s++) {
                        acc = __builtin_amdgcn_mfma_f32_16x16x32_f16(ka[kt][s], qh[sub][s], acc, 0, 0, 0);
                        acc = __builtin_amdgcn_mfma_f32_16x16x32_f16(ka[kt][s], ql[sub][s], acc, 0, 0, 0);
                    }
                    st[sub][kt] = acc;
                }
#pragma unroll
            for (int sub = 0; sub < 2; sub++) {
                float mloc = -1e30f;
#pragma unroll
                for (int kt = 0; kt < 4; kt++)
#pragma unroll
                    for (int r = 0; r < 4; r++) mloc = fmaxf(mloc, st[sub][kt][r]);
                mloc = fmaxf(mloc, __shfl_xor(mloc, 16));
                mloc = fmaxf(mloc, __shfl_xor(mloc, 32));
                float m_new = fmaxf(m_i[sub], mloc);
                float alpha = __expf(m_i[sub] - m_new);
                float ps = 0.f;
#pragma unroll
                for (int kt = 0; kt < 4; kt++) {
                    half4 pk;
#pragma unroll
                    for (int r = 0; r < 4; r++) {
                        float p = __expf(st[sub][kt][r] - m_new);
                        ps += p;
                        pk[r] = (_Float16)p;
                    }
                    int s = kt >> 1;
                    int qd2 = (kt & 1) * 2 + (quad >> 1);
                    *(half4*)(&PTF[wv][sub * 1024 + (s * 64 + qd2 * 16 + qi) * 8 + (quad & 1) * 4]) = pk;
                }
                ps += __shfl_xor(ps, 16);
                ps += __shfl_xor(ps, 32);
                l_i[sub] = l_i[sub] * alpha + ps;
                m_i[sub] = m_new;
#pragma unroll
                for (int ft = 0; ft < 4; ft++) Oacc[sub][ft] *= alpha;
            }
            half8 pb[2][2];
#pragma unroll
            for (int sub = 0; sub < 2; sub++)
#pragma unroll
                for (int s = 0; s < 2; s++)
                    pb[sub][s] = *(const half8*)(&PTF[wv][sub * 1024 + (s * 64 + lane) * 8]);
#pragma unroll
            for (int ft = 0; ft < 4; ft++)
#pragma unroll
                for (int s = 0; s < 2; s++) {
                    half8 v = *(const half8*)(VsF + (ft * 4 + ch * 2 + s) * 512 + lane * 8);
                    Oacc[0][ft] = __builtin_amdgcn_mfma_f32_16x16x32_f16(v, pb[0][s], Oacc[0][ft], 0, 0, 0);
                    Oacc[1][ft] = __builtin_amdgcn_mfma_f32_16x16x32_f16(v, pb[1][s], Oacc[1][ft], 0, 0, 0);
                }
        }
    }
#pragma unroll
    for (int sub = 0; sub < 2; sub++) {
#pragma unroll
        for (int ft = 0; ft < 4; ft++) {
            half4 o;
#pragma unroll
            for (int r = 0; r < 4; r++) o[r] = (_Float16)Oacc[sub][ft][r];
            *(half4*)(Op + ((size_t)sp * NPTS + q0w + sub * 16 + qi) * 64 + ft * 16 + quad * 4) = o;
        }
        if (lane < 16) {
            Ms[sp * NPTS + q0w + sub * 16 + lane] = m_i[sub];
            Ls[sp * NPTS + q0w + sub * 16 + lane] = l_i[sub];
        }
    }
}

// ---------------- merge partials + @Wt (MFMA) + fused BN-stats ----------------
__global__ __launch_bounds__(256) void merge_gemm(const _Float16* __restrict__ Op,
                                                  const float* __restrict__ Ms, const float* __restrict__ Ls,
                                                  const _Float16* __restrict__ Wtf,
                                                  float* __restrict__ xr, float* __restrict__ stats_out) {
    __shared__ float w8[64][8];
    __shared__ float Linv[64];
    __shared__ __align__(16) _Float16 Ah[64 * 72], Al[64 * 72];
    __shared__ float s_sum[64], s_ss[64];
    int t = threadIdx.x;
    int row0 = blockIdx.x * 64;
    if (t < 64) {
        int q = row0 + t;
        float m[8], M = -1e30f;
#pragma unroll
        for (int s = 0; s < 8; s++) {
            m[s] = Ms[s * NPTS + q];
            M = fmaxf(M, m[s]);
        }
        float L = 0.f;
#pragma unroll
        for (int s = 0; s < 8; s++) {
            float w = __expf(m[s] - M);
            w8[t][s] = w;
            L += Ls[s * NPTS + q] * w;
        }
        Linv[t] = 1.f / L;
        s_sum[t] = 0.f;
        s_ss[t] = 0.f;
    }
    __syncthreads();
    for (int k = 0; k < 4; k++) {
        int i = t + k * 256;
        int qr = i >> 4, f4 = (i & 15) * 4;
        int q = row0 + qr;
        float acc[4] = {0.f, 0.f, 0.f, 0.f};
#pragma unroll
        for (int s = 0; s < 8; s++) {
            float w = w8[qr][s];
            half4 o = *(const half4*)(Op + ((size_t)s * NPTS + q) * 64 + f4);
#pragma unroll
            for (int c = 0; c < 4; c++) acc[c] += (float)o[c] * w;
        }
        float inv = Linv[qr];
#pragma unroll
        for (int c = 0; c < 4; c++) {
            float val = acc[c] * inv;
            _Float16 h = (_Float16)val;
            Ah[qr * 72 + f4 + c] = h;
            Al[qr * 72 + f4 + c] = (_Float16)(val - (float)h);
        }
    }
    __syncthreads();
    int lane = t & 63, wv = t >> 6;
    int quad = lane >> 4, qi = lane & 15;
    int rloc = wv * 16 + qi;
    half8 ah[2], al[2];
#pragma unroll
    for (int s = 0; s < 2; s++) {
        ah[s] = *(const half8*)(Ah + rloc * 72 + s * 32 + quad * 8);
        al[s] = *(const half8*)(Al + rloc * 72 + s * 32 + quad * 8);
    }
    floatx4 C[4];
#pragma unroll
    for (int ct = 0; ct < 4; ct++) C[ct] = floatx4{0.f, 0.f, 0.f, 0.f};
#pragma unroll
    for (int ct = 0; ct < 4; ct++)
#pragma unroll
        for (int s = 0; s < 2; s++) {
            half8 b = *(const half8*)(Wtf + (s * 4 + ct) * 512 + lane * 8);
            C[ct] = __builtin_amdgcn_mfma_f32_16x16x32_f16(ah[s], b, C[ct], 0, 0, 0);
            C[ct] = __builtin_amdgcn_mfma_f32_16x16x32_f16(al[s], b, C[ct], 0, 0, 0);
        }
    int orow = row0 + wv * 16 + quad * 4;
#pragma unroll
    for (int ct = 0; ct < 4; ct++) {
        int f = ct * 16 + qi;
        float ps = 0.f, pss = 0.f;
#pragma unroll
        for (int r = 0; r < 4; r++) {
            float v = C[ct][r];
            xr[(size_t)(orow + r) * 64 + f] = v;
            ps += v;
            pss += v * v;
        }
        atomicAdd(&s_sum[f], ps);
        atomicAdd(&s_ss[f], pss);
    }
    __syncthreads();
    if (t < 64) {
        atomicAdd(&stats_out[t], s_sum[t]);
        atomicAdd(&stats_out[64 + t], s_ss[t]);
    }
}

// ---------------- Stage-2 ragged flash attention (unchanged) ----------------
__global__ __launch_bounds__(256) void flash2_mfma(const _Float16* __restrict__ Qh,
                                                   const _Float16* __restrict__ Ql,
                                                   const _Float16* __restrict__ Kh,
                                                   const _Float16* __restrict__ Vt2,
                                                   const int* __restrict__ pad_idx,
                                                   const int* __restrict__ counts,
                                                   _Float16* __restrict__ O) {
    int b = blockIdx.y;
    int c = counts[b];
    int qb = blockIdx.x;
    if (qb * 64 >= c) return;
    __shared__ __align__(16) _Float16 KsF[8 * 512];
    __shared__ __align__(16) _Float16 VsF[8 * 512];
    __shared__ __align__(16) _Float16 PTF[4][2 * 512];
    int t = threadIdx.x;
    int lane = t & 63, wv = t >> 6;
    int quad = lane >> 4, qi = lane & 15;
    const int* prow = pad_idx + b * LQPAD;
    int p_q = qb * 64 + wv * 16 + qi;
    int flat_q = (p_q < LQPAD) ? prow[p_q] : -1;

    half8 qh[2], ql[2];
#pragma unroll
    for (int s = 0; s < 2; s++) {
        if (flat_q >= 0) {
            qh[s] = *(const half8*)(Qh + (size_t)flat_q * 64 + s * 32 + quad * 8);
            ql[s] = *(const half8*)(Ql + (size_t)flat_q * 64 + s * 32 + quad * 8);
        } else {
            qh[s] = half8{0, 0, 0, 0, 0, 0, 0, 0};
            ql[s] = half8{0, 0, 0, 0, 0, 0, 0, 0};
        }
    }
    floatx4 Oacc[4];
#pragma unroll
    for (int ft = 0; ft < 4; ft++) Oacc[ft] = floatx4{0.f, 0.f, 0.f, 0.f};
    float m_i = -1e30f, l_i = 0.f;
    const _Float16* VtB = Vt2 + (size_t)b * 64 * LPAD2;

    int nt = (c + 63) >> 6;
    for (int it = 0; it < nt; it++) {
        int k0 = it * 64;
        __syncthreads();
#pragma unroll
        for (int u = 0; u < 4; u++) {
            int frag = wv + 4 * u;
            if (frag < 8) {
                int kt = frag >> 1, s = frag & 1;
                int kp = k0 + kt * 16 + qi;
                int flat = (kp < c) ? prow[kp] : -1;
                int d0 = s * 32 + quad * 8;
                half8 kvv = half8{0, 0, 0, 0, 0, 0, 0, 0};
                if (flat >= 0) kvv = *(const half8*)(Kh + (size_t)flat * 64 + d0);
                *(half8*)(KsF + frag * 512 + lane * 8) = kvv;
            } else {
                int fr = frag - 8;
                int ft = fr >> 1, s = fr & 1;
                int f = ft * 16 + qi;
                int key = k0 + s * 32 + quad * 8;
                *(half8*)(VsF + fr * 512 + lane * 8) = *(const half8*)(VtB + f * LPAD2 + key);
            }
        }
        __syncthreads();
        floatx4 st[4];
#pragma unroll
        for (int kt = 0; kt < 4; kt++) {
            floatx4 acc = floatx4{0.f, 0.f, 0.f, 0.f};
#pragma unroll
            for (int s = 0; s < 2; s++) {
                half8 a = *(const half8*)(KsF + (kt * 2 + s) * 512 + lane * 8);
                acc = __builtin_amdgcn_mfma_f32_16x16x32_f16(a, qh[s], acc, 0, 0, 0);
                acc = __builtin_amdgcn_mfma_f32_16x16x32_f16(a, ql[s], acc, 0, 0, 0);
            }
            st[kt] = acc;
        }
        float mloc = -1e30f;
#pragma unroll
        for (int kt = 0; kt < 4; kt++)
#pragma unroll
            for (int r = 0; r < 4; r++) mloc = fmaxf(mloc, st[kt][r]);
        mloc = fmaxf(mloc, __shfl_xor(mloc, 16));
        mloc = fmaxf(mloc, __shfl_xor(mloc, 32));
        float m_new = fmaxf(m_i, mloc);
        float alpha = __expf(m_i - m_new);
        float ps = 0.f;
#pragma unroll
        for (int kt = 0; kt < 4; kt++) {
            half4 pk;
#pragma unroll
            for (int r = 0; r < 4; r++) {
                int kpos = k0 + kt * 16 + quad * 4 + r;
                float p = (kpos < c) ? __expf(st[kt][r] - m_new) : 0.f;
                ps += p;
                pk[r] = (_Float16)p;
            }
            int s = kt >> 1;
            int qd2 = (kt & 1) * 2 + (quad >> 1);
            *(half4*)(&PTF[wv][(s * 64 + qd2 * 16 + qi) * 8 + (quad & 1) * 4]) = pk;
        }
        ps += __shfl_xor(ps, 16);
        ps += __shfl_xor(ps, 32);
        l_i = l_i * alpha + ps;
        m_i = m_new;
#pragma unroll
        for (int ft = 0; ft < 4; ft++) Oacc[ft] *= alpha;
        half8 pb[2];
#pragma unroll
        for (int s = 0; s < 2; s++) pb[s] = *(const half8*)(&PTF[wv][(s * 64 + lane) * 8]);
#pragma unroll
        for (int ft = 0; ft < 4; ft++)
#pragma unroll
            for (int s = 0; s < 2; s++) {
                half8 a = *(const half8*)(VsF + (ft * 2 + s) * 512 + lane * 8);
                Oacc[ft] = __builtin_amdgcn_mfma_f32_16x16x32_f16(a, pb[s], Oacc[ft], 0, 0, 0);
            }
    }
    if (flat_q >= 0) {
        float inv = 1.f / l_i;
#pragma unroll
        for (int ft = 0; ft < 4; ft++) {
            half4 o;
#pragma unroll
            for (int r = 0; r < 4; r++) o[r] = (_Float16)(Oacc[ft][r] * inv);
            *(half4*)(O + (size_t)flat_q * 64 + ft * 16 + quad * 4) = o;
        }
    }
}

extern "C" void kernel_launch(void* const* d_in, const int* in_sizes, int n_in,
                              void* d_out, int out_size, void* d_ws, size_t ws_size,
                              hipStream_t stream) {
    const float* x_dec = (const float*)d_in[0];
    const float* x_enc = (const float*)d_in[1];
    const float* Wp1 = (const float*)d_in[2];
    const float* Wq = (const float*)d_in[3];
    const float* Wk = (const float*)d_in[4];
    const float* Wv = (const float*)d_in[5];
    const float* Wt_ = (const float*)d_in[6];
    const float* Wq1 = (const float*)d_in[7];
    const float* Wk1 = (const float*)d_in[8];
    const float* Wv1 = (const float*)d_in[9];
    const float* Wdown = (const float*)d_in[10];
    const float* W3t = (const float*)d_in[11];
    const float* W3a = (const float*)d_in[12];
    const float* W3b = (const float*)d_in[13];
    const float* bn_g = (const float*)d_in[14];
    const float* bn_b = (const float*)d_in[15];
    const int* nbr = (const int*)d_in[16];
    const int* kv_nbr = (const int*)d_in[17];
    const int* pad_idx = (const int*)d_in[18];
    const int* unpad_idx = (const int*)d_in[19];
    float* out = (float*)d_out;
    float* ws = (float*)d_ws;

    const int N = NPTS;
    const size_t BUF = (size_t)N * 64;
    float* xd = ws;
    float* slot1 = ws + BUF;
    float* slot2 = ws + 2 * BUF;
    float* slot3 = ws + 3 * BUF;
    float* slot4 = ws + 4 * BUF;
    float* slot5 = ws + 5 * BUF;
    float* slot6 = ws + 6 * BUF;
    float* slot7 = ws + 7 * BUF;
    float* slot8 = ws + 8 * BUF;
    float* arena = ws + 9 * BUF;

    float* stats = arena;
    int* counts = (int*)(arena + 768);
    float* Ms = arena + 1024;
    float* Ls = Ms + 8 * NPTS;
    _Float16* WfA = (_Float16*)(Ls + 8 * NPTS);
    float* Wpq = (float*)(WfA + (size_t)97 * 4096);

    _Float16* Oph = (_Float16*)slot1;
    _Float16* Qh = (_Float16*)slot5;
    _Float16* Ql = Qh + BUF;
    _Float16* Kh = (_Float16*)slot6;
    _Float16* Vt = Kh + BUF;
    float* kv = slot5;
    _Float16* Qh1 = (_Float16*)slot2;
    _Float16* Ql1 = Qh1 + BUF;
    _Float16* Kh1 = (_Float16*)slot6;
    _Float16* Vt2 = (_Float16*)slot1;
    _Float16* z2h = (_Float16*)slot4;
    float* xr = slot7;
    _Float16* xrh = (_Float16*)slot7;
    float* xr2 = slot8;
    float* o2 = slot8;
    _Float16* xr2h = (_Float16*)slot6;
    float* z2 = slot3;

    const _Float16* Wtf = WfA + 4 * 4096;
    const _Float16* Wq1f = WfA + 5 * 4096;
    const _Float16* Wk1f = WfA + 6 * 4096;
    const _Float16* Wv1f = WfA + 7 * 4096;
    const _Float16* Wdf = WfA + 8 * 4096;
    const _Float16* W3tf = WfA + (size_t)16 * 4096;
    const _Float16* W3af = WfA + (size_t)43 * 4096;
    const _Float16* W3bf = WfA + (size_t)70 * 4096;

    hipMemsetAsync(stats, 0, 1024 * sizeof(float), stream);

    dim3 B(256);
    int gG = N / 64;      // 192
    int gC2 = 2 * gG;     // 384: f-split gconvs

    wprod16<<<16, B, 0, stream>>>(Wp1, Wq, Wpq);
    pack_all<<<97, B, 0, stream>>>(Wp1, Wpq, Wk, Wv, Wt_, Wq1, Wk1, Wv1, Wdown, W3t, W3a, W3b, WfA);
    count_valid<<<8, B, 0, stream>>>(pad_idx, counts);

    gemm_head<<<dim3(gG, 4), B, 0, stream>>>(x_dec, x_enc, WfA, xd, Qh, Ql, Kh, Vt);
    flash1_mfma<<<dim3(N / 128, 8), B, 0, stream>>>(Qh, Ql, Kh, Vt, Oph, Ms, Ls);
    merge_gemm<<<gG, B, 0, stream>>>(Oph, Ms, Ls, Wtf, xr, stats + 0);
    gemm_q1<<<gG, B, 0, stream>>>(xr, xd, Wq1f, stats + 0, bn_g + 0, bn_b + 0, Qh1, Ql1);

    gconv_mfma<<<gC2, B, 0, stream>>>(Qh1, kv_nbr, Wdf, kv, 8, nullptr, stats + 128);
    gemm_kv1<<<dim3(gG, 2), B, 0, stream>>>(kv, Wk1f, Wv1f, stats + 128, bn_g + 64, bn_b + 64,
                                            unpad_idx, Kh1, Vt2);
    flash2_mfma<<<dim3(LPAD2 / 64, 8), B, 0, stream>>>(Qh1, Ql1, Kh1, Vt2, pad_idx, counts, z2h);
    gconv_mfma<<<gC2, B, 0, stream>>>(z2h, nbr, W3tf, xr2, 27, nullptr, stats + 256);
    bn_apply<<<256, B, 0, stream>>>(xr2, nullptr, xd, xd, nullptr, stats + 256, bn_g + 128, bn_b + 128,
                                    stats + 384, N, 0);

    bn_apply<<<256, B, 0, stream>>>(xd, nullptr, nullptr, nullptr, xrh, stats + 384, bn_g + 192,
                                    bn_b + 192, nullptr, N, 1);
    gconv_mfma<<<gC2, B, 0, stream>>>(xrh, nbr, W3af, o2, 27, nullptr, stats + 512);
    bn_apply<<<256, B, 0, stream>>>(o2, nullptr, nullptr, nullptr, xr2h, stats + 512, bn_g + 256,
                                    bn_b + 256, nullptr, N, 1);
    gconv_mfma<<<gC2, B, 0, stream>>>(xr2h, nbr, W3bf, z2, 27, xd, stats + 640);
    bn_apply<<<256, B, 0, stream>>>(xd, z2, nullptr, out, nullptr, stats + 640, bn_g + 320, bn_b + 320,
                                    nullptr, N, 1);
}

// Round 9
// 408.968 us; speedup vs baseline: 1.7555x; 1.0152x over previous
//
#include <hip/hip_runtime.h>

#define NPTS 12288
#define LQPAD 1800
#define LPAD2 1856
#define EPSBN 1e-4f

typedef _Float16 half8 __attribute__((ext_vector_type(8)));
typedef _Float16 half4 __attribute__((ext_vector_type(4)));
typedef float floatx4 __attribute__((ext_vector_type(4)));

// ---------------- Wpq = Wp1 @ Wq (fp32, 16 blocks x 4 rows) ----------------
__global__ __launch_bounds__(256) void wprod16(const float* __restrict__ Wp1, const float* __restrict__ Wq,
                                               float* __restrict__ Wpq) {
    __shared__ float Bs[4096];
    __shared__ float As[4][64];
    int t = threadIdx.x;
    for (int i = t; i < 4096; i += 256) Bs[i] = Wq[i];
    int r0 = blockIdx.x * 4;
    {
        int i = t >> 6, k = t & 63;
        As[i][k] = Wp1[(r0 + i) * 64 + k];
    }
    __syncthreads();
    int i = t >> 6, j = t & 63;
    float s = 0.f;
#pragma unroll
    for (int k = 0; k < 64; k++) s += As[i][k] * Bs[k * 64 + j];
    Wpq[(r0 + i) * 64 + j] = s;
}

// ---------------- pack ALL weights into B-fragment-major fp16 arena ----------------
__global__ __launch_bounds__(256) void pack_all(const float* Wp1, const float* Wpq, const float* Wk,
                                                const float* Wv, const float* Wt_, const float* Wq1,
                                                const float* Wk1, const float* Wv1, const float* Wdown,
                                                const float* W3t, const float* W3a, const float* W3b,
                                                _Float16* __restrict__ Wf) {
    int g = blockIdx.x;
    const float* src;
    if (g == 0) src = Wp1;
    else if (g == 1) src = Wpq;
    else if (g == 2) src = Wk;
    else if (g == 3) src = Wv;
    else if (g == 4) src = Wt_;
    else if (g == 5) src = Wq1;
    else if (g == 6) src = Wk1;
    else if (g == 7) src = Wv1;
    else if (g < 16) src = Wdown + (size_t)(g - 8) * 4096;
    else if (g < 43) src = W3t + (size_t)(g - 16) * 4096;
    else if (g < 70) src = W3a + (size_t)(g - 43) * 4096;
    else src = W3b + (size_t)(g - 70) * 4096;
    int t = threadIdx.x;
    int lane = t & 63, fg = t >> 6;
    int quad = lane >> 4, qi = lane & 15;
#pragma unroll
    for (int u = 0; u < 2; u++) {
        int frag = fg * 2 + u;
        int s = frag >> 2, ct = frag & 3;
        half8 v;
#pragma unroll
        for (int j = 0; j < 8; j++) v[j] = (_Float16)src[(s * 32 + quad * 8 + j) * 64 + ct * 16 + qi];
        *(half8*)(Wf + (size_t)g * 4096 + frag * 512 + lane * 8) = v;
    }
}

// A fp32 row -> hi/lo half8 fragments
__device__ inline void load_split8(const float* p, half8& hi, half8& lo) {
    float4 a = *(const float4*)p;
    float4 b = *(const float4*)(p + 4);
    float v[8] = {a.x, a.y, a.z, a.w, b.x, b.y, b.z, b.w};
#pragma unroll
    for (int j = 0; j < 8; j++) {
        _Float16 h = (_Float16)v[j];
        hi[j] = h;
        lo[j] = (_Float16)(v[j] - (float)h);
    }
}

// ---------------- gemm_head: 4 GEMMs in one launch (stage-1 inputs) ----------------
// y=0: xd (fp32)  y=1: Qh fp16  y=2: Kh fp16  y=3: Vt transposed fp16
__global__ __launch_bounds__(256) void gemm_head(const float* __restrict__ xdec, const float* __restrict__ xenc,
                                                 const _Float16* __restrict__ Wf, float* __restrict__ xd,
                                                 _Float16* __restrict__ Qh,
                                                 _Float16* __restrict__ Kh, _Float16* __restrict__ Vt) {
    int z = blockIdx.y;
    const float* A = (z < 2) ? xdec : xenc;
    const _Float16* Bf = Wf + (size_t)z * 4096;
    int t = threadIdx.x;
    int lane = t & 63, wv = t >> 6;
    int quad = lane >> 4, qi = lane & 15;
    int row0w = blockIdx.x * 64 + wv * 16;
    half8 ah[2], al[2];
#pragma unroll
    for (int s = 0; s < 2; s++) load_split8(A + (size_t)(row0w + qi) * 64 + s * 32 + quad * 8, ah[s], al[s]);
    floatx4 C[4];
#pragma unroll
    for (int ct = 0; ct < 4; ct++) C[ct] = floatx4{0.f, 0.f, 0.f, 0.f};
#pragma unroll
    for (int ct = 0; ct < 4; ct++)
#pragma unroll
        for (int s = 0; s < 2; s++) {
            half8 b = *(const half8*)(Bf + (s * 4 + ct) * 512 + lane * 8);
            C[ct] = __builtin_amdgcn_mfma_f32_16x16x32_f16(ah[s], b, C[ct], 0, 0, 0);
            C[ct] = __builtin_amdgcn_mfma_f32_16x16x32_f16(al[s], b, C[ct], 0, 0, 0);
        }
    int orow = row0w + quad * 4;
    if (z == 0) {
#pragma unroll
        for (int ct = 0; ct < 4; ct++)
#pragma unroll
            for (int r = 0; r < 4; r++) xd[(size_t)(orow + r) * 64 + ct * 16 + qi] = C[ct][r];
    } else if (z == 1) {
#pragma unroll
        for (int ct = 0; ct < 4; ct++)
#pragma unroll
            for (int r = 0; r < 4; r++) Qh[(size_t)(orow + r) * 64 + ct * 16 + qi] = (_Float16)C[ct][r];
    } else if (z == 2) {
#pragma unroll
        for (int ct = 0; ct < 4; ct++)
#pragma unroll
            for (int r = 0; r < 4; r++) Kh[(size_t)(orow + r) * 64 + ct * 16 + qi] = (_Float16)C[ct][r];
    } else {
#pragma unroll
        for (int ct = 0; ct < 4; ct++) {
            half4 o;
#pragma unroll
            for (int r = 0; r < 4; r++) o[r] = (_Float16)C[ct][r];
            *(half4*)(Vt + (size_t)(ct * 16 + qi) * NPTS + orow) = o;
        }
    }
}

// ---------------- gemm_q1: fused [xd += BN(xr)] prologue + q1 = xd@Wq1 (fp16 out) ---------
__global__ __launch_bounds__(256) void gemm_q1(const float* __restrict__ xr, float* __restrict__ xd,
                                               const _Float16* __restrict__ Bf,
                                               const float* __restrict__ stats,
                                               const float* __restrict__ gamma,
                                               const float* __restrict__ beta,
                                               _Float16* __restrict__ Oh) {
    int t = threadIdx.x;
    int lane = t & 63, wv = t >> 6;
    int quad = lane >> 4, qi = lane & 15;
    int row0w = blockIdx.x * 64 + wv * 16;
    const float inv_n = 1.f / (float)NPTS;
    half8 ah[2], al[2];
#pragma unroll
    for (int s = 0; s < 2; s++) {
        size_t base = (size_t)(row0w + qi) * 64 + s * 32 + quad * 8;
        float4 xa = *(const float4*)(xr + base);
        float4 xb = *(const float4*)(xr + base + 4);
        float4 da = *(const float4*)(xd + base);
        float4 db = *(const float4*)(xd + base + 4);
        float vx[8] = {xa.x, xa.y, xa.z, xa.w, xb.x, xb.y, xb.z, xb.w};
        float vd[8] = {da.x, da.y, da.z, da.w, db.x, db.y, db.z, db.w};
        float vo[8];
#pragma unroll
        for (int j = 0; j < 8; j++) {
            int f = s * 32 + quad * 8 + j;
            float mean = stats[f] * inv_n;
            float var = stats[64 + f] * inv_n - mean * mean;
            float val = vd[j] + (vx[j] - mean) * rsqrtf(var + EPSBN) * gamma[f] + beta[f];
            vo[j] = val;
            _Float16 h = (_Float16)val;
            ah[s][j] = h;
            al[s][j] = (_Float16)(val - (float)h);
        }
        *(float4*)(xd + base) = float4{vo[0], vo[1], vo[2], vo[3]};
        *(float4*)(xd + base + 4) = float4{vo[4], vo[5], vo[6], vo[7]};
    }
    floatx4 C[4];
#pragma unroll
    for (int ct = 0; ct < 4; ct++) C[ct] = floatx4{0.f, 0.f, 0.f, 0.f};
#pragma unroll
    for (int ct = 0; ct < 4; ct++)
#pragma unroll
        for (int s = 0; s < 2; s++) {
            half8 b = *(const half8*)(Bf + (s * 4 + ct) * 512 + lane * 8);
            C[ct] = __builtin_amdgcn_mfma_f32_16x16x32_f16(ah[s], b, C[ct], 0, 0, 0);
            C[ct] = __builtin_amdgcn_mfma_f32_16x16x32_f16(al[s], b, C[ct], 0, 0, 0);
        }
    int orow = row0w + quad * 4;
#pragma unroll
    for (int ct = 0; ct < 4; ct++)
#pragma unroll
        for (int r = 0; r < 4; r++) Oh[(size_t)(orow + r) * 64 + ct * 16 + qi] = (_Float16)C[ct][r];
}

// ---------------- gemm_kv1: BN(kv) fused prologue; y=0 -> Kh1, y=1 -> Vt2 scatter ---------
__global__ __launch_bounds__(256) void gemm_kv1(const float* __restrict__ kv, const _Float16* __restrict__ Wfk,
                                                const _Float16* __restrict__ Wfv,
                                                const float* __restrict__ stats, const float* __restrict__ gamma,
                                                const float* __restrict__ beta, const int* __restrict__ unpad,
                                                _Float16* __restrict__ Kh1, _Float16* __restrict__ Vt2) {
    int y = blockIdx.y;
    int t = threadIdx.x;
    int lane = t & 63, wv = t >> 6;
    int quad = lane >> 4, qi = lane & 15;
    int row0w = blockIdx.x * 64 + wv * 16;
    const float inv_n = 1.f / (float)NPTS;
    half8 ah[2], al[2];
#pragma unroll
    for (int s = 0; s < 2; s++) {
        const float* p = kv + (size_t)(row0w + qi) * 64 + s * 32 + quad * 8;
        float4 a = *(const float4*)p;
        float4 b2 = *(const float4*)(p + 4);
        float v[8] = {a.x, a.y, a.z, a.w, b2.x, b2.y, b2.z, b2.w};
#pragma unroll
        for (int j = 0; j < 8; j++) {
            int f = s * 32 + quad * 8 + j;
            float mean = stats[f] * inv_n;
            float var = stats[64 + f] * inv_n - mean * mean;
            float val = (v[j] - mean) * rsqrtf(var + EPSBN) * gamma[f] + beta[f];
            _Float16 h = (_Float16)val;
            ah[s][j] = h;
            al[s][j] = (_Float16)(val - (float)h);
        }
    }
    const _Float16* Bf = y ? Wfv : Wfk;
    floatx4 C[4];
#pragma unroll
    for (int ct = 0; ct < 4; ct++) C[ct] = floatx4{0.f, 0.f, 0.f, 0.f};
#pragma unroll
    for (int ct = 0; ct < 4; ct++)
#pragma unroll
        for (int s = 0; s < 2; s++) {
            half8 b = *(const half8*)(Bf + (s * 4 + ct) * 512 + lane * 8);
            C[ct] = __builtin_amdgcn_mfma_f32_16x16x32_f16(ah[s], b, C[ct], 0, 0, 0);
            C[ct] = __builtin_amdgcn_mfma_f32_16x16x32_f16(al[s], b, C[ct], 0, 0, 0);
        }
    int orow = row0w + quad * 4;
    if (y == 0) {
#pragma unroll
        for (int ct = 0; ct < 4; ct++)
#pragma unroll
            for (int r = 0; r < 4; r++) Kh1[(size_t)(orow + r) * 64 + ct * 16 + qi] = (_Float16)C[ct][r];
    } else {
        int u0 = unpad[orow], u3 = unpad[orow + 3];
        int b0 = u0 / 1800, b3 = u3 / 1800;
        if (u3 == u0 + 3 && b0 == b3) {
            int p0 = u0 - b0 * 1800;
#pragma unroll
            for (int ct = 0; ct < 4; ct++) {
                half4 o;
#pragma unroll
                for (int r = 0; r < 4; r++) o[r] = (_Float16)C[ct][r];
                *(half4*)(Vt2 + ((size_t)b0 * 64 + ct * 16 + qi) * LPAD2 + p0) = o;
            }
        } else {
#pragma unroll
            for (int r = 0; r < 4; r++) {
                int u = unpad[orow + r];
                int b = u / 1800, p = u - b * 1800;
#pragma unroll
                for (int ct = 0; ct < 4; ct++)
                    Vt2[((size_t)b * 64 + ct * 16 + qi) * LPAD2 + p] = (_Float16)C[ct][r];
            }
        }
    }
}

// ---------------- gather conv, MFMA, f-split x2, depth-1 software pipeline ----------------
__global__ __launch_bounds__(256) void gconv_mfma(const _Float16* __restrict__ Xh,
                                                  const int* __restrict__ idx,
                                                  const _Float16* __restrict__ Wf,
                                                  float* __restrict__ OUT, int nk,
                                                  const float* Xadd, float* stats_out) {
    __shared__ float s_sum[64], s_ss[64];
    int t = threadIdx.x;
    int lane = t & 63, wv = t >> 6;
    int quad = lane >> 4, qi = lane & 15;
    int bx = blockIdx.x;
    int row0 = (bx >> 1) * 64 + wv * 16;
    int cb = (bx & 1) * 2;
    if (stats_out) {
        if (t < 64) {
            s_sum[t] = 0.f;
            s_ss[t] = 0.f;
        }
        __syncthreads();
    }
    floatx4 Oacc[2];
#pragma unroll
    for (int u = 0; u < 2; u++) Oacc[u] = floatx4{0.f, 0.f, 0.f, 0.f};
    const int* ip = idx + (size_t)(row0 + qi) * nk;
    // pipeline: A-fragments for tap k prefetched during tap k-1's MFMAs
    int j = ip[0];
    half8 a0 = half8{0, 0, 0, 0, 0, 0, 0, 0};
    half8 a1 = half8{0, 0, 0, 0, 0, 0, 0, 0};
    if (j >= 0) {
        a0 = *(const half8*)(Xh + (size_t)j * 64 + quad * 8);
        a1 = *(const half8*)(Xh + (size_t)j * 64 + 32 + quad * 8);
    }
    for (int k = 0; k < nk; k++) {
        half8 n0 = half8{0, 0, 0, 0, 0, 0, 0, 0};
        half8 n1 = half8{0, 0, 0, 0, 0, 0, 0, 0};
        if (k + 1 < nk) {
            int jn = ip[k + 1];
            if (jn >= 0) {
                n0 = *(const half8*)(Xh + (size_t)jn * 64 + quad * 8);
                n1 = *(const half8*)(Xh + (size_t)jn * 64 + 32 + quad * 8);
            }
        }
        const _Float16* wk = Wf + (size_t)k * 4096;
#pragma unroll
        for (int u = 0; u < 2; u++) {
            int ct = cb + u;
            half8 b0 = *(const half8*)(wk + ct * 512 + lane * 8);
            half8 b1 = *(const half8*)(wk + (4 + ct) * 512 + lane * 8);
            Oacc[u] = __builtin_amdgcn_mfma_f32_16x16x32_f16(a0, b0, Oacc[u], 0, 0, 0);
            Oacc[u] = __builtin_amdgcn_mfma_f32_16x16x32_f16(a1, b1, Oacc[u], 0, 0, 0);
        }
        a0 = n0;
        a1 = n1;
    }
    int orow = row0 + quad * 4;
#pragma unroll
    for (int u = 0; u < 2; u++) {
        int ct = cb + u;
#pragma unroll
        for (int r = 0; r < 4; r++) OUT[(size_t)(orow + r) * 64 + ct * 16 + qi] = Oacc[u][r];
    }
    if (stats_out) {
#pragma unroll
        for (int u = 0; u < 2; u++) {
            int f = (cb + u) * 16 + qi;
            float ps = 0.f, pss = 0.f;
#pragma unroll
            for (int r = 0; r < 4; r++) {
                float v = Oacc[u][r];
                if (Xadd) v += Xadd[(size_t)(orow + r) * 64 + f];
                ps += v;
                pss += v * v;
            }
            atomicAdd(&s_sum[f], ps);
            atomicAdd(&s_ss[f], pss);
        }
        __syncthreads();
        if (t < 64) {
            atomicAdd(&stats_out[t], s_sum[t]);
            atomicAdd(&stats_out[64 + t], s_ss[t]);
        }
    }
}

// ---------------- bn_apply ----------------
__global__ __launch_bounds__(256) void bn_apply(const float* __restrict__ X, const float* X2,
                                                const float* R, float* OUT, _Float16* OUT16,
                                                const float* __restrict__ stats,
                                                const float* __restrict__ gamma,
                                                const float* __restrict__ beta,
                                                float* stats_out, int n, int do_relu) {
    __shared__ float sh[2][4][64];
    int t = threadIdx.x;
    int f = t & 63, g = t >> 6;
    float inv_n = 1.f / (float)n;
    float mean = stats[f] * inv_n;
    float var = stats[64 + f] * inv_n - mean * mean;
    float rstd = rsqrtf(var + EPSBN);
    float ga = gamma[f], be = beta[f];
    float s = 0.f, ss = 0.f;
    for (int r = blockIdx.x * 4 + g; r < n; r += gridDim.x * 4) {
        size_t i = (size_t)r * 64 + f;
        float v = X[i];
        if (X2) v += X2[i];
        v = (v - mean) * rstd * ga + be;
        if (R) v += R[i];
        if (do_relu) v = fmaxf(v, 0.f);
        if (OUT) OUT[i] = v;
        if (OUT16) OUT16[i] = (_Float16)v;
        s += v;
        ss += v * v;
    }
    if (stats_out) {
        sh[0][g][f] = s;
        sh[1][g][f] = ss;
        __syncthreads();
        if (g == 0) {
            s = sh[0][0][f] + sh[0][1][f] + sh[0][2][f] + sh[0][3][f];
            ss = sh[1][0][f] + sh[1][1][f] + sh[1][2][f] + sh[1][3][f];
            atomicAdd(&stats_out[f], s);
            atomicAdd(&stats_out[64 + f], ss);
        }
    }
}

// ---------------- per-batch valid counts ----------------
__global__ __launch_bounds__(256) void count_valid(const int* __restrict__ pad_idx, int* __restrict__ counts) {
    int b = blockIdx.x;
    int t = threadIdx.x;
    int s = 0;
    for (int i = t; i < LQPAD; i += 256) s += (pad_idx[b * LQPAD + i] >= 0) ? 1 : 0;
    for (int off = 32; off > 0; off >>= 1) s += __shfl_xor(s, off);
    if ((t & 63) == 0) atomicAdd(&counts[b], s);
}

// ---------------- Stage-1 flash attention: K=64 tiles, 32 q-rows/wave, fp16 Q ------------
__global__ __launch_bounds__(256, 3) void flash1_mfma(const _Float16* __restrict__ Qh,
                                                      const _Float16* __restrict__ Kh,
                                                      const _Float16* __restrict__ Vt,
                                                      _Float16* __restrict__ Op,
                                                      float* __restrict__ Ms,
                                                      float* __restrict__ Ls) {
    __shared__ __align__(16) _Float16 KsF[8 * 512];
    __shared__ __align__(16) _Float16 VsF[8 * 512];
    __shared__ __align__(16) _Float16 PTF[4][2 * 1024];
    int t = threadIdx.x;
    int lane = t & 63, wv = t >> 6;
    int quad = lane >> 4, qi = lane & 15;
    int qb = blockIdx.x, sp = blockIdx.y;
    int q0w = qb * 128 + wv * 32;

    half8 qh[2][2];
#pragma unroll
    for (int sub = 0; sub < 2; sub++)
#pragma unroll
        for (int s = 0; s < 2; s++) {
            int qrow = q0w + sub * 16 + qi;
            qh[sub][s] = *(const half8*)(Qh + (size_t)qrow * 64 + s * 32 + quad * 8);
        }
    floatx4 Oacc[2][4];
#pragma unroll
    for (int sub = 0; sub < 2; sub++)
#pragma unroll
        for (int ft = 0; ft < 4; ft++) Oacc[sub][ft] = floatx4{0.f, 0.f, 0.f, 0.f};
    float m_i[2] = {-1e30f, -1e30f}, l_i[2] = {0.f, 0.f};

    for (int it = 0; it < 24; it++) {
        int k0 = sp * 1536 + it * 64;
        __syncthreads();
#pragma unroll
        for (int u = 0; u < 4; u++) {
            int frag = wv + 4 * u;
            if (frag < 8) {
                int kt = frag >> 1, s = frag & 1;
                int key = k0 + kt * 16 + qi;
                *(half8*)(KsF + frag * 512 + lane * 8) =
                    *(const half8*)(Kh + (size_t)key * 64 + s * 32 + quad * 8);
            } else {
                int fr = frag - 8;
                int ft = fr >> 1, s = fr & 1;
                int f = ft * 16 + qi;
                *(half8*)(VsF + fr * 512 + lane * 8) =
                    *(const half8*)(Vt + (size_t)f * NPTS + k0 + s * 32 + quad * 8);
            }
        }
        __syncthreads();
        half8 ka[4][2];
#pragma unroll
        for (int kt = 0; kt < 4; kt++)
#pragma unroll
            for (int s = 0; s < 2; s++) ka[kt][s] = *(const half8*)(KsF + (kt * 2 + s) * 512 + lane * 8);
        floatx4 st[2][4];
#pragma unroll
        for (int sub = 0; sub < 2; sub++)
#pragma unroll
            for (int kt = 0; kt < 4; kt++) {
                floatx4 acc = floatx4{0.f, 0.f, 0.f, 0.f};
#pragma unroll
                for (int s = 0; s < 2; s++)
                    acc = __builtin_amdgcn_mfma_f32_16x16x32_f16(ka[kt][s], qh[sub][s], acc, 0, 0, 0);
                st[sub][kt] = acc;
            }
#pragma unroll
        for (int sub = 0; sub < 2; sub++) {
            float mloc = -1e30f;
#pragma unroll
            for (int kt = 0; kt < 4; kt++)
#pragma unroll
                for (int r = 0; r < 4; r++) mloc = fmaxf(mloc, st[sub][kt][r]);
            mloc = fmaxf(mloc, __shfl_xor(mloc, 16));
            mloc = fmaxf(mloc, __shfl_xor(mloc, 32));
            float m_new = fmaxf(m_i[sub], mloc);
            float alpha = __expf(m_i[sub] - m_new);
            float ps = 0.f;
#pragma unroll
            for (int kt = 0; kt < 4; kt++) {
                half4 pk;
#pragma unroll
                for (int r = 0; r < 4; r++) {
                    float p = __expf(st[sub][kt][r] - m_new);
                    ps += p;
                    pk[r] = (_Float16)p;
                }
                int s = kt >> 1;
                int qd2 = (kt & 1) * 2 + (quad >> 1);
                *(half4*)(&PTF[wv][sub * 1024 + (s * 64 + qd2 * 16 + qi) * 8 + (quad & 1) * 4]) = pk;
            }
            ps += __shfl_xor(ps, 16);
            ps += __shfl_xor(ps, 32);
            l_i[sub] = l_i[sub] * alpha + ps;
            m_i[sub] = m_new;
#pragma unroll
            for (int ft = 0; ft < 4; ft++) Oacc[sub][ft] *= alpha;
        }
        half8 pb[2][2];
#pragma unroll
        for (int sub = 0; sub < 2; sub++)
#pragma unroll
            for (int s = 0; s < 2; s++)
                pb[sub][s] = *(const half8*)(&PTF[wv][sub * 1024 + (s * 64 + lane) * 8]);
#pragma unroll
        for (int ft = 0; ft < 4; ft++)
#pragma unroll
            for (int s = 0; s < 2; s++) {
                half8 v = *(const half8*)(VsF + (ft * 2 + s) * 512 + lane * 8);
                Oacc[0][ft] = __builtin_amdgcn_mfma_f32_16x16x32_f16(v, pb[0][s], Oacc[0][ft], 0, 0, 0);
                Oacc[1][ft] = __builtin_amdgcn_mfma_f32_16x16x32_f16(v, pb[1][s], Oacc[1][ft], 0, 0, 0);
            }
    }
#pragma unroll
    for (int sub = 0; sub < 2; sub++) {
#pragma unroll
        for (int ft = 0; ft < 4; ft++) {
            half4 o;
#pragma unroll
            for (int r = 0; r < 4; r++) o[r] = (_Float16)Oacc[sub][ft][r];
            *(half4*)(Op + ((size_t)sp * NPTS + q0w + sub * 16 + qi) * 64 + ft * 16 + quad * 4) = o;
        }
        if (lane < 16) {
            Ms[sp * NPTS + q0w + sub * 16 + lane] = m_i[sub];
            Ls[sp * NPTS + q0w + sub * 16 + lane] = l_i[sub];
        }
    }
}

// ---------------- merge partials + @Wt (MFMA) + fused BN-stats ----------------
__global__ __launch_bounds__(256) void merge_gemm(const _Float16* __restrict__ Op,
                                                  const float* __restrict__ Ms, const float* __restrict__ Ls,
                                                  const _Float16* __restrict__ Wtf,
                                                  float* __restrict__ xr, float* __restrict__ stats_out) {
    __shared__ float w8[64][8];
    __shared__ float Linv[64];
    __shared__ __align__(16) _Float16 Ah[64 * 72], Al[64 * 72];
    __shared__ float s_sum[64], s_ss[64];
    int t = threadIdx.x;
    int row0 = blockIdx.x * 64;
    if (t < 64) {
        int q = row0 + t;
        float m[8], M = -1e30f;
#pragma unroll
        for (int s = 0; s < 8; s++) {
            m[s] = Ms[s * NPTS + q];
            M = fmaxf(M, m[s]);
        }
        float L = 0.f;
#pragma unroll
        for (int s = 0; s < 8; s++) {
            float w = __expf(m[s] - M);
            w8[t][s] = w;
            L += Ls[s * NPTS + q] * w;
        }
        Linv[t] = 1.f / L;
        s_sum[t] = 0.f;
        s_ss[t] = 0.f;
    }
    __syncthreads();
    for (int k = 0; k < 4; k++) {
        int i = t + k * 256;
        int qr = i >> 4, f4 = (i & 15) * 4;
        int q = row0 + qr;
        float acc[4] = {0.f, 0.f, 0.f, 0.f};
#pragma unroll
        for (int s = 0; s < 8; s++) {
            float w = w8[qr][s];
            half4 o = *(const half4*)(Op + ((size_t)s * NPTS + q) * 64 + f4);
#pragma unroll
            for (int c = 0; c < 4; c++) acc[c] += (float)o[c] * w;
        }
        float inv = Linv[qr];
#pragma unroll
        for (int c = 0; c < 4; c++) {
            float val = acc[c] * inv;
            _Float16 h = (_Float16)val;
            Ah[qr * 72 + f4 + c] = h;
            Al[qr * 72 + f4 + c] = (_Float16)(val - (float)h);
        }
    }
    __syncthreads();
    int lane = t & 63, wv = t >> 6;
    int quad = lane >> 4, qi = lane & 15;
    int rloc = wv * 16 + qi;
    half8 ah[2], al[2];
#pragma unroll
    for (int s = 0; s < 2; s++) {
        ah[s] = *(const half8*)(Ah + rloc * 72 + s * 32 + quad * 8);
        al[s] = *(const half8*)(Al + rloc * 72 + s * 32 + quad * 8);
    }
    floatx4 C[4];
#pragma unroll
    for (int ct = 0; ct < 4; ct++) C[ct] = floatx4{0.f, 0.f, 0.f, 0.f};
#pragma unroll
    for (int ct = 0; ct < 4; ct++)
#pragma unroll
        for (int s = 0; s < 2; s++) {
            half8 b = *(const half8*)(Wtf + (s * 4 + ct) * 512 + lane * 8);
            C[ct] = __builtin_amdgcn_mfma_f32_16x16x32_f16(ah[s], b, C[ct], 0, 0, 0);
            C[ct] = __builtin_amdgcn_mfma_f32_16x16x32_f16(al[s], b, C[ct], 0, 0, 0);
        }
    int orow = row0 + wv * 16 + quad * 4;
#pragma unroll
    for (int ct = 0; ct < 4; ct++) {
        int f = ct * 16 + qi;
        float ps = 0.f, pss = 0.f;
#pragma unroll
        for (int r = 0; r < 4; r++) {
            float v = C[ct][r];
            xr[(size_t)(orow + r) * 64 + f] = v;
            ps += v;
            pss += v * v;
        }
        atomicAdd(&s_sum[f], ps);
        atomicAdd(&s_ss[f], pss);
    }
    __syncthreads();
    if (t < 64) {
        atomicAdd(&stats_out[t], s_sum[t]);
        atomicAdd(&stats_out[64 + t], s_ss[t]);
    }
}

// ---------------- Stage-2 ragged flash attention, fp16 Q ----------------
__global__ __launch_bounds__(256) void flash2_mfma(const _Float16* __restrict__ Qh,
                                                   const _Float16* __restrict__ Kh,
                                                   const _Float16* __restrict__ Vt2,
                                                   const int* __restrict__ pad_idx,
                                                   const int* __restrict__ counts,
                                                   _Float16* __restrict__ O) {
    int b = blockIdx.y;
    int c = counts[b];
    int qb = blockIdx.x;
    if (qb * 64 >= c) return;
    __shared__ __align__(16) _Float16 KsF[8 * 512];
    __shared__ __align__(16) _Float16 VsF[8 * 512];
    __shared__ __align__(16) _Float16 PTF[4][2 * 512];
    int t = threadIdx.x;
    int lane = t & 63, wv = t >> 6;
    int quad = lane >> 4, qi = lane & 15;
    const int* prow = pad_idx + b * LQPAD;
    int p_q = qb * 64 + wv * 16 + qi;
    int flat_q = (p_q < LQPAD) ? prow[p_q] : -1;

    half8 qh[2];
#pragma unroll
    for (int s = 0; s < 2; s++) {
        qh[s] = (flat_q >= 0) ? *(const half8*)(Qh + (size_t)flat_q * 64 + s * 32 + quad * 8)
                              : half8{0, 0, 0, 0, 0, 0, 0, 0};
    }
    floatx4 Oacc[4];
#pragma unroll
    for (int ft = 0; ft < 4; ft++) Oacc[ft] = floatx4{0.f, 0.f, 0.f, 0.f};
    float m_i = -1e30f, l_i = 0.f;
    const _Float16* VtB = Vt2 + (size_t)b * 64 * LPAD2;

    int nt = (c + 63) >> 6;
    for (int it = 0; it < nt; it++) {
        int k0 = it * 64;
        __syncthreads();
#pragma unroll
        for (int u = 0; u < 4; u++) {
            int frag = wv + 4 * u;
            if (frag < 8) {
                int kt = frag >> 1, s = frag & 1;
                int kp = k0 + kt * 16 + qi;
                int flat = (kp < c) ? prow[kp] : -1;
                int d0 = s * 32 + quad * 8;
                half8 kvv = half8{0, 0, 0, 0, 0, 0, 0, 0};
                if (flat >= 0) kvv = *(const half8*)(Kh + (size_t)flat * 64 + d0);
                *(half8*)(KsF + frag * 512 + lane * 8) = kvv;
            } else {
                int fr = frag - 8;
                int ft = fr >> 1, s = fr & 1;
                int f = ft * 16 + qi;
                int key = k0 + s * 32 + quad * 8;
                *(half8*)(VsF + fr * 512 + lane * 8) = *(const half8*)(VtB + f * LPAD2 + key);
            }
        }
        __syncthreads();
        floatx4 st[4];
#pragma unroll
        for (int kt = 0; kt < 4; kt++) {
            floatx4 acc = floatx4{0.f, 0.f, 0.f, 0.f};
#pragma unroll
            for (int s = 0; s < 2; s++) {
                half8 a = *(const half8*)(KsF + (kt * 2 + s) * 512 + lane * 8);
                acc = __builtin_amdgcn_mfma_f32_16x16x32_f16(a, qh[s], acc, 0, 0, 0);
            }
            st[kt] = acc;
        }
        float mloc = -1e30f;
#pragma unroll
        for (int kt = 0; kt < 4; kt++)
#pragma unroll
            for (int r = 0; r < 4; r++) mloc = fmaxf(mloc, st[kt][r]);
        mloc = fmaxf(mloc, __shfl_xor(mloc, 16));
        mloc = fmaxf(mloc, __shfl_xor(mloc, 32));
        float m_new = fmaxf(m_i, mloc);
        float alpha = __expf(m_i - m_new);
        float ps = 0.f;
#pragma unroll
        for (int kt = 0; kt < 4; kt++) {
            half4 pk;
#pragma unroll
            for (int r = 0; r < 4; r++) {
                int kpos = k0 + kt * 16 + quad * 4 + r;
                float p = (kpos < c) ? __expf(st[kt][r] - m_new) : 0.f;
                ps += p;
                pk[r] = (_Float16)p;
            }
            int s = kt >> 1;
            int qd2 = (kt & 1) * 2 + (quad >> 1);
            *(half4*)(&PTF[wv][(s * 64 + qd2 * 16 + qi) * 8 + (quad & 1) * 4]) = pk;
        }
        ps += __shfl_xor(ps, 16);
        ps += __shfl_xor(ps, 32);
        l_i = l_i * alpha + ps;
        m_i = m_new;
#pragma unroll
        for (int ft = 0; ft < 4; ft++) Oacc[ft] *= alpha;
        half8 pb[2];
#pragma unroll
        for (int s = 0; s < 2; s++) pb[s] = *(const half8*)(&PTF[wv][(s * 64 + lane) * 8]);
#pragma unroll
        for (int ft = 0; ft < 4; ft++)
#pragma unroll
            for (int s = 0; s < 2; s++) {
                half8 a = *(const half8*)(VsF + (ft * 2 + s) * 512 + lane * 8);
                Oacc[ft] = __builtin_amdgcn_mfma_f32_16x16x32_f16(a, pb[s], Oacc[ft], 0, 0, 0);
            }
    }
    if (flat_q >= 0) {
        float inv = 1.f / l_i;
#pragma unroll
        for (int ft = 0; ft < 4; ft++) {
            half4 o;
#pragma unroll
            for (int r = 0; r < 4; r++) o[r] = (_Float16)(Oacc[ft][r] * inv);
            *(half4*)(O + (size_t)flat_q * 64 + ft * 16 + quad * 4) = o;
        }
    }
}

extern "C" void kernel_launch(void* const* d_in, const int* in_sizes, int n_in,
                              void* d_out, int out_size, void* d_ws, size_t ws_size,
                              hipStream_t stream) {
    const float* x_dec = (const float*)d_in[0];
    const float* x_enc = (const float*)d_in[1];
    const float* Wp1 = (const float*)d_in[2];
    const float* Wq = (const float*)d_in[3];
    const float* Wk = (const float*)d_in[4];
    const float* Wv = (const float*)d_in[5];
    const float* Wt_ = (const float*)d_in[6];
    const float* Wq1 = (const float*)d_in[7];
    const float* Wk1 = (const float*)d_in[8];
    const float* Wv1 = (const float*)d_in[9];
    const float* Wdown = (const float*)d_in[10];
    const float* W3t = (const float*)d_in[11];
    const float* W3a = (const float*)d_in[12];
    const float* W3b = (const float*)d_in[13];
    const float* bn_g = (const float*)d_in[14];
    const float* bn_b = (const float*)d_in[15];
    const int* nbr = (const int*)d_in[16];
    const int* kv_nbr = (const int*)d_in[17];
    const int* pad_idx = (const int*)d_in[18];
    const int* unpad_idx = (const int*)d_in[19];
    float* out = (float*)d_out;
    float* ws = (float*)d_ws;

    const int N = NPTS;
    const size_t BUF = (size_t)N * 64;
    float* xd = ws;
    float* slot1 = ws + BUF;
    float* slot2 = ws + 2 * BUF;
    float* slot3 = ws + 3 * BUF;
    float* slot4 = ws + 4 * BUF;
    float* slot5 = ws + 5 * BUF;
    float* slot6 = ws + 6 * BUF;
    float* slot7 = ws + 7 * BUF;
    float* slot8 = ws + 8 * BUF;
    float* arena = ws + 9 * BUF;

    float* stats = arena;
    int* counts = (int*)(arena + 768);
    float* Ms = arena + 1024;
    float* Ls = Ms + 8 * NPTS;
    _Float16* WfA = (_Float16*)(Ls + 8 * NPTS);
    float* Wpq = (float*)(WfA + (size_t)97 * 4096);

    _Float16* Oph = (_Float16*)slot1;
    _Float16* Qh = (_Float16*)slot5;
    _Float16* Kh = (_Float16*)slot6;
    _Float16* Vt = Kh + BUF;
    float* kv = slot5;
    _Float16* Qh1 = (_Float16*)slot2;
    _Float16* Kh1 = (_Float16*)slot6;
    _Float16* Vt2 = (_Float16*)slot1;
    _Float16* z2h = (_Float16*)slot4;
    float* xr = slot7;
    _Float16* xrh = (_Float16*)slot7;
    float* xr2 = slot8;
    float* o2 = slot8;
    _Float16* xr2h = (_Float16*)slot6;
    float* z2 = slot3;

    const _Float16* Wtf = WfA + 4 * 4096;
    const _Float16* Wq1f = WfA + 5 * 4096;
    const _Float16* Wk1f = WfA + 6 * 4096;
    const _Float16* Wv1f = WfA + 7 * 4096;
    const _Float16* Wdf = WfA + 8 * 4096;
    const _Float16* W3tf = WfA + (size_t)16 * 4096;
    const _Float16* W3af = WfA + (size_t)43 * 4096;
    const _Float16* W3bf = WfA + (size_t)70 * 4096;

    hipMemsetAsync(stats, 0, 1024 * sizeof(float), stream);

    dim3 B(256);
    int gG = N / 64;      // 192
    int gC2 = 2 * gG;     // 384: f-split gconvs

    wprod16<<<16, B, 0, stream>>>(Wp1, Wq, Wpq);
    pack_all<<<97, B, 0, stream>>>(Wp1, Wpq, Wk, Wv, Wt_, Wq1, Wk1, Wv1, Wdown, W3t, W3a, W3b, WfA);
    count_valid<<<8, B, 0, stream>>>(pad_idx, counts);

    gemm_head<<<dim3(gG, 4), B, 0, stream>>>(x_dec, x_enc, WfA, xd, Qh, Kh, Vt);
    flash1_mfma<<<dim3(N / 128, 8), B, 0, stream>>>(Qh, Kh, Vt, Oph, Ms, Ls);
    merge_gemm<<<gG, B, 0, stream>>>(Oph, Ms, Ls, Wtf, xr, stats + 0);
    gemm_q1<<<gG, B, 0, stream>>>(xr, xd, Wq1f, stats + 0, bn_g + 0, bn_b + 0, Qh1);

    gconv_mfma<<<gC2, B, 0, stream>>>(Qh1, kv_nbr, Wdf, kv, 8, nullptr, stats + 128);
    gemm_kv1<<<dim3(gG, 2), B, 0, stream>>>(kv, Wk1f, Wv1f, stats + 128, bn_g + 64, bn_b + 64,
                                            unpad_idx, Kh1, Vt2);
    flash2_mfma<<<dim3(LPAD2 / 64, 8), B, 0, stream>>>(Qh1, Kh1, Vt2, pad_idx, counts, z2h);
    gconv_mfma<<<gC2, B, 0, stream>>>(z2h, nbr, W3tf, xr2, 27, nullptr, stats + 256);
    bn_apply<<<256, B, 0, stream>>>(xr2, nullptr, xd, xd, nullptr, stats + 256, bn_g + 128, bn_b + 128,
                                    stats + 384, N, 0);

    bn_apply<<<256, B, 0, stream>>>(xd, nullptr, nullptr, nullptr, xrh, stats + 384, bn_g + 192,
                                    bn_b + 192, nullptr, N, 1);
    gconv_mfma<<<gC2, B, 0, stream>>>(xrh, nbr, W3af, o2, 27, nullptr, stats + 512);
    bn_apply<<<256, B, 0, stream>>>(o2, nullptr, nullptr, nullptr, xr2h, stats + 512, bn_g + 256,
                                    bn_b + 256, nullptr, N, 1);
    gconv_mfma<<<gC2, B, 0, stream>>>(xr2h, nbr, W3bf, z2, 27, xd, stats + 640);
    bn_apply<<<256, B, 0, stream>>>(xd, z2, nullptr, out, nullptr, stats + 640, bn_g + 320, bn_b + 320,
                                    nullptr, N, 1);
}